// Round 2
// baseline (836.846 us; speedup 1.0000x reference)
//
#include <hip/hip_runtime.h>
#include <math.h>

// Problem dims
constexpr int T0n = 2048;   // tokens
constexpr int Dn  = 2048;   // hidden
constexpr int En  = 256;    // experts
constexpr int Kn  = 8;      // top-k
constexpr int Gn  = 8;      // groups
constexpr int EGn = 32;     // experts per group
constexpr int Rn  = 64;     // tucker rank
constexpr int In  = 1408;   // intermediate

constexpr int NROWS = T0n * Kn;   // 16384 dispatched rows
constexpr int SEGCAP = NROWS;     // per-group segment capacity in rseg

// ---------------------------------------------------------------------------
// Generic fp32 tiled GEMM tile: C[m0:m0+32, n0C:n0C+64] = A[M,K] @ B[K,N]
// BM=32, BN=64, BK=32, 256 threads, 2x4 micro-tile per thread.
// ---------------------------------------------------------------------------
__device__ __forceinline__ void gemm_tile(
    const float* __restrict__ A, int lda,
    const float* __restrict__ B, int ldb,
    float* __restrict__ C, int ldc,
    int Kdim, int m0, int n0B, int n0C)
{
  __shared__ float As[32][33];   // [k][m], +1 pad
  __shared__ float Bs[32][64];   // [k][n]
  const int tid = threadIdx.x;
  const int ty = tid >> 4, tx = tid & 15;
  const int lm  = tid >> 3;         // A-load row 0..31
  const int lk4 = (tid & 7) << 2;   // A-load k offset 0,4,..,28

  float acc[2][4] = {{0.f,0.f,0.f,0.f},{0.f,0.f,0.f,0.f}};

  for (int k0 = 0; k0 < Kdim; k0 += 32) {
    float4 av = *(const float4*)&A[(size_t)(m0 + lm) * lda + k0 + lk4];
    As[lk4 + 0][lm] = av.x;
    As[lk4 + 1][lm] = av.y;
    As[lk4 + 2][lm] = av.z;
    As[lk4 + 3][lm] = av.w;
#pragma unroll
    for (int q = 0; q < 2; ++q) {
      int idx = tid * 2 + q;
      int br = idx >> 4, bc = (idx & 15) << 2;
      *(float4*)&Bs[br][bc] = *(const float4*)&B[(size_t)(k0 + br) * ldb + n0B + bc];
    }
    __syncthreads();
#pragma unroll
    for (int kk = 0; kk < 32; ++kk) {
      float a0 = As[kk][ty * 2 + 0];
      float a1 = As[kk][ty * 2 + 1];
      float4 bv = *(const float4*)&Bs[kk][tx << 2];
      acc[0][0] += a0 * bv.x; acc[0][1] += a0 * bv.y;
      acc[0][2] += a0 * bv.z; acc[0][3] += a0 * bv.w;
      acc[1][0] += a1 * bv.x; acc[1][1] += a1 * bv.y;
      acc[1][2] += a1 * bv.z; acc[1][3] += a1 * bv.w;
    }
    __syncthreads();
  }
#pragma unroll
  for (int i = 0; i < 2; ++i) {
    float4 o;
    o.x = acc[i][0]; o.y = acc[i][1]; o.z = acc[i][2]; o.w = acc[i][3];
    *(float4*)&C[(size_t)(m0 + ty * 2 + i) * ldc + n0C + (tx << 2)] = o;
  }
}

__global__ __launch_bounds__(256) void k_gemm_plain(
    const float* __restrict__ A, int lda, const float* __restrict__ B, int ldb,
    float* __restrict__ C, int ldc, int Kdim)
{
  gemm_tile(A, lda, B, ldb, C, ldc, Kdim,
            blockIdx.y * 32, blockIdx.x * 64, blockIdx.x * 64);
}

// ---------------------------------------------------------------------------
// Router logits GEMM with FP64 accumulation. The top-8 selection is discrete:
// sequential-fp32 noise (~1e-4 on logits) flips the rank-8/9 boundary for
// ~1% of tokens vs np's pairwise summation (~1e-6 noise). fp64 accumulation
// gives the true ordering, which np also resolves. Products are fp32 inputs
// widened to double; output stored fp32 (6e-8 rounding << logit gaps).
// ---------------------------------------------------------------------------
__global__ __launch_bounds__(256) void k_router(
    const float* __restrict__ A,   // hidden [2048, 2048]
    const float* __restrict__ B,   // w_gate [2048, 256]
    float* __restrict__ C)         // logits [2048, 256]
{
  __shared__ float As[32][33];
  __shared__ float Bs[32][64];
  const int m0 = blockIdx.y * 32, n0 = blockIdx.x * 64;
  const int tid = threadIdx.x;
  const int ty = tid >> 4, tx = tid & 15;
  const int lm  = tid >> 3;
  const int lk4 = (tid & 7) << 2;

  double acc[2][4] = {{0.0,0.0,0.0,0.0},{0.0,0.0,0.0,0.0}};

  for (int k0 = 0; k0 < Dn; k0 += 32) {
    float4 av = *(const float4*)&A[(size_t)(m0 + lm) * Dn + k0 + lk4];
    As[lk4 + 0][lm] = av.x;
    As[lk4 + 1][lm] = av.y;
    As[lk4 + 2][lm] = av.z;
    As[lk4 + 3][lm] = av.w;
#pragma unroll
    for (int q = 0; q < 2; ++q) {
      int idx = tid * 2 + q;
      int br = idx >> 4, bc = (idx & 15) << 2;
      *(float4*)&Bs[br][bc] = *(const float4*)&B[(size_t)(k0 + br) * En + n0 + bc];
    }
    __syncthreads();
#pragma unroll
    for (int kk = 0; kk < 32; ++kk) {
      double a0 = (double)As[kk][ty * 2 + 0];
      double a1 = (double)As[kk][ty * 2 + 1];
      float4 bv = *(const float4*)&Bs[kk][tx << 2];
      acc[0][0] += a0 * (double)bv.x; acc[0][1] += a0 * (double)bv.y;
      acc[0][2] += a0 * (double)bv.z; acc[0][3] += a0 * (double)bv.w;
      acc[1][0] += a1 * (double)bv.x; acc[1][1] += a1 * (double)bv.y;
      acc[1][2] += a1 * (double)bv.z; acc[1][3] += a1 * (double)bv.w;
    }
    __syncthreads();
  }
#pragma unroll
  for (int i = 0; i < 2; ++i) {
    float4 o;
    o.x = (float)acc[i][0]; o.y = (float)acc[i][1];
    o.z = (float)acc[i][2]; o.w = (float)acc[i][3];
    *(float4*)&C[(size_t)(m0 + ty * 2 + i) * En + n0 + (tx << 2)] = o;
  }
}

// h1[t, g*64+r] = H @ A_fac[g];  z selects gate(0)/up(1) path, blockIdx.x = group
__global__ __launch_bounds__(256) void k_gemm_h1(
    const float* __restrict__ H,
    const float* __restrict__ Agate, const float* __restrict__ Aup,
    float* __restrict__ h1g, float* __restrict__ h1u)
{
  int g = blockIdx.x;
  const float* Af = (blockIdx.z ? Aup : Agate) + (size_t)g * Dn * Rn;
  float* out = blockIdx.z ? h1u : h1g;
  gemm_tile(H, Dn, Af, Rn, out, Gn * Rn, Dn, blockIdx.y * 32, 0, g * Rn);
}

// ---------------------------------------------------------------------------
// Router top-8: one block per token. Selection on logits == selection on
// softmax (monotone); rw_k = exp(l_k - max) / sum_top8 exp(l - max).
// ---------------------------------------------------------------------------
__global__ __launch_bounds__(256) void k_topk(
    const float* __restrict__ logits, int* __restrict__ sel,
    float* __restrict__ rw, int* __restrict__ cnt_e)
{
  int t = blockIdx.x, tid = threadIdx.x;
  __shared__ float pv[256];
  __shared__ float rv[256];
  __shared__ int   ri[256];
  __shared__ float topv[8];
  __shared__ int   topi[8];
  pv[tid] = logits[(size_t)t * En + tid];
  __syncthreads();
  for (int k = 0; k < 8; ++k) {
    rv[tid] = pv[tid]; ri[tid] = tid;
    __syncthreads();
    for (int s = 128; s > 0; s >>= 1) {
      if (tid < s) {
        float v2 = rv[tid + s]; int i2 = ri[tid + s];
        if (v2 > rv[tid] || (v2 == rv[tid] && i2 < ri[tid])) {
          rv[tid] = v2; ri[tid] = i2;
        }
      }
      __syncthreads();
    }
    if (tid == 0) { topv[k] = rv[0]; topi[k] = ri[0]; pv[ri[0]] = -1e30f; }
    __syncthreads();
  }
  if (tid < 8) {
    float m = topv[0];
    float ssum = 0.f;
#pragma unroll
    for (int k = 0; k < 8; ++k) ssum += expf(topv[k] - m);
    rw[t * 8 + tid]  = expf(topv[tid] - m) / ssum;
    sel[t * 8 + tid] = topi[tid];
    atomicAdd(&cnt_e[topi[tid]], 1);
  }
}

// Serial 256-entry scan; writes per-expert offsets inside per-group segments.
__global__ void k_scan(const int* __restrict__ cnt_e, int* __restrict__ off_e,
                       int* __restrict__ cur_e, int* __restrict__ grp_n)
{
  if (threadIdx.x == 0 && blockIdx.x == 0) {
    for (int g = 0; g < Gn; ++g) {
      int run = 0;
      for (int ei = 0; ei < EGn; ++ei) {
        int e = g * EGn + ei;
        off_e[e] = g * SEGCAP + run;
        cur_e[e] = g * SEGCAP + run;
        run += cnt_e[e];
      }
      grp_n[g] = run;
    }
  }
}

__global__ void k_scatter(const int* __restrict__ sel, int* __restrict__ cur_e,
                          int* __restrict__ rseg)
{
  int i = blockIdx.x * 256 + threadIdx.x;   // dispatched row id
  int e = sel[i];
  int pos = atomicAdd(&cur_e[e], 1);
  rseg[pos] = i;
}

// ---------------------------------------------------------------------------
// Per-expert core (gate/up): h2[i,s] = sum_r h1[t,g,r] * C[e][r][s]
// One block per expert; C_gate/C_up staged in LDS.
// ---------------------------------------------------------------------------
__global__ __launch_bounds__(256) void k_core_gu(
    const float* __restrict__ h1g, const float* __restrict__ h1u,
    const float* __restrict__ Cgate, const float* __restrict__ Cup,
    const int* __restrict__ rseg, const int* __restrict__ off_e,
    const int* __restrict__ cnt_e,
    float* __restrict__ h2g, float* __restrict__ h2u)
{
  const int e = blockIdx.x;
  const int ne = cnt_e[e];
  if (ne == 0) return;
  const int g = e >> 5;
  const int base = off_e[e];
  __shared__ float Cg[64 * 64];
  __shared__ float Cu[64 * 64];
  __shared__ float Hg[4 * 64];
  __shared__ float Hu[4 * 64];
  const int tid = threadIdx.x;
  {
    const float* cg = Cgate + (size_t)e * (Rn * Rn);
    const float* cu = Cup   + (size_t)e * (Rn * Rn);
    int r = tid >> 2, q = (tid & 3) << 4;
#pragma unroll
    for (int i = 0; i < 4; ++i) {
      *(float4*)&Cg[r * 64 + q + i * 4] = *(const float4*)&cg[r * 64 + q + i * 4];
      *(float4*)&Cu[r * 64 + q + i * 4] = *(const float4*)&cu[r * 64 + q + i * 4];
    }
  }
  __syncthreads();
  const int j = tid >> 6, s = tid & 63;
  const int iters = (ne + 3) >> 2;
  for (int it = 0; it < iters; ++it) {
    int mi = (it << 2) + j;
    int rid = (mi < ne) ? rseg[base + mi] : -1;
    Hg[tid] = (rid >= 0) ? h1g[(size_t)(rid >> 3) * (Gn * Rn) + g * Rn + s] : 0.f;
    Hu[tid] = (rid >= 0) ? h1u[(size_t)(rid >> 3) * (Gn * Rn) + g * Rn + s] : 0.f;
    __syncthreads();
    float ag = 0.f, au = 0.f;
#pragma unroll 16
    for (int r = 0; r < 64; ++r) {
      ag += Hg[(j << 6) + r] * Cg[r * 64 + s];
      au += Hu[(j << 6) + r] * Cu[r * 64 + s];
    }
    if (rid >= 0) {
      h2g[(size_t)rid * 64 + s] = ag;
      h2u[(size_t)rid * 64 + s] = au;
    }
    __syncthreads();
  }
}

// ---------------------------------------------------------------------------
// Fused expand + down-A, per group:
//   inter = silu(h2g @ B_gate[g]) * (h2u @ B_up[g])   (64-row x 64-col tiles)
//   h1d[row,:] += inter_tile @ A_down[g][n0:n0+64, :]  (fp32 atomics)
// inter never touches HBM. blockIdx = (n-split 0/1, row-tile, group).
// ---------------------------------------------------------------------------
#define FMA4(ACC, AV, BV) \
  ACC[0] += (AV) * (BV).x; ACC[1] += (AV) * (BV).y; \
  ACC[2] += (AV) * (BV).z; ACC[3] += (AV) * (BV).w;

__global__ __launch_bounds__(256) void k_expand(
    const float* __restrict__ h2g, const float* __restrict__ h2u,
    const float* __restrict__ Bgate, const float* __restrict__ Bup,
    const float* __restrict__ Adown,
    const int* __restrict__ rseg, const int* __restrict__ grp_n,
    float* __restrict__ h1d)
{
  const int g = blockIdx.z;
  const int ng = grp_n[g];
  const int m0 = blockIdx.y * 64;
  if (m0 >= ng) return;
  const int xs = blockIdx.x;   // 0 or 1 (11 chunks each)

  __shared__ float HgT[64 * 68];   // [r][row], stride 68 keeps float4 align
  __shared__ float HuT[64 * 68];
  __shared__ float S1[64 * 68];    // B_gate chunk, then inter tile
  __shared__ float S2[64 * 64];    // B_up chunk, then A_down chunk
  __shared__ int rids[64];

  const int tid = threadIdx.x;
  {
    int j = tid >> 2, q = tid & 3;
    int mi = m0 + j;
    int rid = (mi < ng) ? rseg[g * SEGCAP + mi] : -1;
    if (q == 0) rids[j] = rid;
#pragma unroll
    for (int i = 0; i < 4; ++i) {
      int kb = q * 16 + i * 4;
      float4 vg, vu;
      if (rid >= 0) {
        vg = *(const float4*)&h2g[(size_t)rid * 64 + kb];
        vu = *(const float4*)&h2u[(size_t)rid * 64 + kb];
      } else {
        vg = make_float4(0.f, 0.f, 0.f, 0.f);
        vu = make_float4(0.f, 0.f, 0.f, 0.f);
      }
      HgT[(kb + 0) * 68 + j] = vg.x; HgT[(kb + 1) * 68 + j] = vg.y;
      HgT[(kb + 2) * 68 + j] = vg.z; HgT[(kb + 3) * 68 + j] = vg.w;
      HuT[(kb + 0) * 68 + j] = vu.x; HuT[(kb + 1) * 68 + j] = vu.y;
      HuT[(kb + 2) * 68 + j] = vu.z; HuT[(kb + 3) * 68 + j] = vu.w;
    }
  }
  __syncthreads();

  const int ty = tid >> 4, tx = tid & 15;
  const float* Bg_base = Bgate + (size_t)g * Rn * In;
  const float* Bu_base = Bup   + (size_t)g * Rn * In;
  const float* Ad_base = Adown + (size_t)g * In * Rn;

  const int lr = tid >> 2, lq = (tid & 3) << 4;
  float P[4][4] = {};

  for (int c = 0; c < 11; ++c) {
    const int n0 = (xs * 11 + c) * 64;
    // stage B_gate -> S1 (stride 68), B_up -> S2 (stride 64)
#pragma unroll
    for (int i = 0; i < 4; ++i) {
      *(float4*)&S1[lr * 68 + lq + i * 4] =
          *(const float4*)&Bg_base[(size_t)lr * In + n0 + lq + i * 4];
      *(float4*)&S2[lr * 64 + lq + i * 4] =
          *(const float4*)&Bu_base[(size_t)lr * In + n0 + lq + i * 4];
    }
    __syncthreads();

    float ag[4][4] = {}; float au[4][4] = {};
#pragma unroll 4
    for (int kk = 0; kk < 64; ++kk) {
      float4 hg = *(const float4*)&HgT[kk * 68 + (ty << 2)];
      float4 hu = *(const float4*)&HuT[kk * 68 + (ty << 2)];
      float4 bg = *(const float4*)&S1[kk * 68 + (tx << 2)];
      float4 bu = *(const float4*)&S2[kk * 64 + (tx << 2)];
      FMA4(ag[0], hg.x, bg); FMA4(ag[1], hg.y, bg);
      FMA4(ag[2], hg.z, bg); FMA4(ag[3], hg.w, bg);
      FMA4(au[0], hu.x, bu); FMA4(au[1], hu.y, bu);
      FMA4(au[2], hu.z, bu); FMA4(au[3], hu.w, bu);
    }
    __syncthreads();

    // inter = silu(gate)*up -> S1 ; stage A_down chunk -> S2
#pragma unroll
    for (int i = 0; i < 4; ++i) {
      float4 o;
      o.x = ag[i][0] / (1.f + expf(-ag[i][0])) * au[i][0];
      o.y = ag[i][1] / (1.f + expf(-ag[i][1])) * au[i][1];
      o.z = ag[i][2] / (1.f + expf(-ag[i][2])) * au[i][2];
      o.w = ag[i][3] / (1.f + expf(-ag[i][3])) * au[i][3];
      *(float4*)&S1[((ty << 2) + i) * 68 + (tx << 2)] = o;
    }
#pragma unroll
    for (int i = 0; i < 4; ++i) {
      *(float4*)&S2[lr * 64 + lq + i * 4] =
          *(const float4*)&Ad_base[(size_t)(n0 + lr) * Rn + lq + i * 4];
    }
    __syncthreads();

    // P += inter_tile @ Ad_chunk
#pragma unroll 4
    for (int nn = 0; nn < 64; nn += 4) {
      float4 b0 = *(const float4*)&S2[(nn + 0) * 64 + (tx << 2)];
      float4 b1 = *(const float4*)&S2[(nn + 1) * 64 + (tx << 2)];
      float4 b2 = *(const float4*)&S2[(nn + 2) * 64 + (tx << 2)];
      float4 b3 = *(const float4*)&S2[(nn + 3) * 64 + (tx << 2)];
#pragma unroll
      for (int i = 0; i < 4; ++i) {
        float4 a = *(const float4*)&S1[((ty << 2) + i) * 68 + nn];
        P[i][0] += a.x * b0.x + a.y * b1.x + a.z * b2.x + a.w * b3.x;
        P[i][1] += a.x * b0.y + a.y * b1.y + a.z * b2.y + a.w * b3.y;
        P[i][2] += a.x * b0.z + a.y * b1.z + a.z * b2.z + a.w * b3.z;
        P[i][3] += a.x * b0.w + a.y * b1.w + a.z * b2.w + a.w * b3.w;
      }
    }
    __syncthreads();
  }

#pragma unroll
  for (int i = 0; i < 4; ++i) {
    int m = (ty << 2) + i;
    if (m0 + m < ng) {
      int rid = rids[m];
#pragma unroll
      for (int jj = 0; jj < 4; ++jj)
        atomicAdd(&h1d[(size_t)rid * 64 + (tx << 2) + jj], P[i][jj]);
    }
  }
}

// ---------------------------------------------------------------------------
// Per-expert down core + routing weight, reduced into dense y[t, g, 64].
// ---------------------------------------------------------------------------
__global__ __launch_bounds__(256) void k_core_down(
    const float* __restrict__ h1d, const float* __restrict__ Cdown,
    const float* __restrict__ rw,
    const int* __restrict__ rseg, const int* __restrict__ off_e,
    const int* __restrict__ cnt_e,
    float* __restrict__ y)
{
  const int e = blockIdx.x;
  const int ne = cnt_e[e];
  if (ne == 0) return;
  const int g = e >> 5;
  const int base = off_e[e];
  __shared__ float Cd[64 * 64];
  __shared__ float Hd[4 * 64];
  const int tid = threadIdx.x;
  {
    const float* cd = Cdown + (size_t)e * (Rn * Rn);
    int r = tid >> 2, q = (tid & 3) << 4;
#pragma unroll
    for (int i = 0; i < 4; ++i)
      *(float4*)&Cd[r * 64 + q + i * 4] = *(const float4*)&cd[r * 64 + q + i * 4];
  }
  __syncthreads();
  const int j = tid >> 6, s = tid & 63;
  const int iters = (ne + 3) >> 2;
  for (int it = 0; it < iters; ++it) {
    int mi = (it << 2) + j;
    int rid = (mi < ne) ? rseg[base + mi] : -1;
    Hd[tid] = (rid >= 0) ? h1d[(size_t)rid * 64 + s] : 0.f;
    __syncthreads();
    float a = 0.f;
#pragma unroll 16
    for (int r = 0; r < 64; ++r)
      a += Hd[(j << 6) + r] * Cd[r * 64 + s];
    if (rid >= 0) {
      float w = rw[rid];
      atomicAdd(&y[(size_t)(rid >> 3) * (Gn * Rn) + g * Rn + s], w * a);
    }
    __syncthreads();
  }
}

// ---------------------------------------------------------------------------
extern "C" void kernel_launch(void* const* d_in, const int* in_sizes, int n_in,
                              void* d_out, int out_size, void* d_ws, size_t ws_size,
                              hipStream_t stream)
{
  const float* hidden = (const float*)d_in[0];
  const float* w_gate = (const float*)d_in[1];
  const float* A_gate = (const float*)d_in[2];
  const float* C_gate = (const float*)d_in[3];
  const float* B_gate = (const float*)d_in[4];
  const float* A_up   = (const float*)d_in[5];
  const float* C_up   = (const float*)d_in[6];
  const float* B_up   = (const float*)d_in[7];
  const float* A_down = (const float*)d_in[8];
  const float* C_down = (const float*)d_in[9];
  const float* B_down = (const float*)d_in[10];
  float* out = (float*)d_out;

  float* ws     = (float*)d_ws;
  float* logits = ws;                          // 2048*256
  float* h1g    = logits + (size_t)T0n * En;   // 2048*512
  float* h1u    = h1g + (size_t)T0n * Gn * Rn;
  float* h2g    = h1u + (size_t)T0n * Gn * Rn; // 16384*64
  float* h2u    = h2g + (size_t)NROWS * Rn;
  float* h1d    = h2u + (size_t)NROWS * Rn;    // 16384*64 (zeroed)
  float* y      = h1d + (size_t)NROWS * Rn;    // 2048*512 (zeroed)
  float* rwp    = y + (size_t)T0n * Gn * Rn;   // 16384
  int* sel   = (int*)(rwp + NROWS);            // 16384
  int* rseg  = sel + NROWS;                    // 8*16384
  int* cnt_e = rseg + Gn * SEGCAP;             // 256
  int* off_e = cnt_e + En;
  int* cur_e = off_e + En;
  int* grp_n = cur_e + En;

  hipMemsetAsync(h1d, 0, (size_t)NROWS * Rn * sizeof(float), stream);
  hipMemsetAsync(y,   0, (size_t)T0n * Gn * Rn * sizeof(float), stream);
  hipMemsetAsync(cnt_e, 0, En * sizeof(int), stream);

  // 1) router logits (fp64 accumulation -> exact expert ordering)
  k_router<<<dim3(En / 64, T0n / 32), 256, 0, stream>>>(hidden, w_gate, logits);
  // 2) dense in-factor projections for all (t, g), gate+up
  k_gemm_h1<<<dim3(Gn, T0n / 32, 2), 256, 0, stream>>>(
      hidden, A_gate, A_up, h1g, h1u);
  // 3) top-8 + renorm + expert counts
  k_topk<<<T0n, 256, 0, stream>>>(logits, sel, rwp, cnt_e);
  // 4) offsets + scatter rows by expert (expert-major => group-major)
  k_scan<<<1, 64, 0, stream>>>(cnt_e, off_e, cur_e, grp_n);
  k_scatter<<<NROWS / 256, 256, 0, stream>>>(sel, cur_e, rseg);
  // 5) per-expert core (gate/up)
  k_core_gu<<<En, 256, 0, stream>>>(h1g, h1u, C_gate, C_up,
                                    rseg, off_e, cnt_e, h2g, h2u);
  // 6) fused expand + down-A (inter stays on-chip)
  k_expand<<<dim3(2, NROWS / 64, Gn), 256, 0, stream>>>(
      h2g, h2u, B_gate, B_up, A_down, rseg, grp_n, h1d);
  // 7) per-expert down core + rw, reduce to y[t,g,:]
  k_core_down<<<En, 256, 0, stream>>>(h1d, C_down, rwp,
                                      rseg, off_e, cnt_e, y);
  // 8) combine: out[2048,2048] = y[2048,512] @ B_down-as-[512,2048]
  k_gemm_plain<<<dim3(Dn / 64, T0n / 32), 256, 0, stream>>>(
      y, Gn * Rn, B_down, Dn, out, Dn, Gn * Rn);
}

// Round 3
// 536.358 us; speedup vs baseline: 1.5602x; 1.5602x over previous
//
#include <hip/hip_runtime.h>
#include <math.h>

// Problem dims
constexpr int T0n = 2048;   // tokens
constexpr int Dn  = 2048;   // hidden
constexpr int En  = 256;    // experts
constexpr int Gn  = 8;      // groups
constexpr int EGn = 32;     // experts per group
constexpr int Rn  = 64;     // tucker rank
constexpr int In  = 1408;   // intermediate

constexpr int NROWS = T0n * 8;    // 16384 dispatched rows
constexpr int SEGCAP = NROWS;     // per-group segment capacity in rseg

typedef __attribute__((ext_vector_type(8))) short s8v;   // 8 bf16
typedef __attribute__((ext_vector_type(4))) float f4v;   // 4 fp32
#define MFMA16(a, b, c) __builtin_amdgcn_mfma_f32_16x16x32_bf16(a, b, c, 0, 0, 0)

__device__ __forceinline__ unsigned short f2bf(float x) {
  unsigned int u = __float_as_uint(x);
  unsigned int r = (u + 0x7FFFu + ((u >> 16) & 1u)) >> 16;
  return (unsigned short)r;
}

// ---------------------------------------------------------------------------
// fp32 -> bf16 elementwise (n multiple of 1024)
// ---------------------------------------------------------------------------
__global__ __launch_bounds__(256) void k_cvt(const float* __restrict__ src,
                                             unsigned short* __restrict__ dst, int n) {
  int i = (blockIdx.x * 256 + threadIdx.x) * 4;
  if (i < n) {
    float4 v = *(const float4*)&src[i];
    ushort4 o;
    o.x = f2bf(v.x); o.y = f2bf(v.y); o.z = f2bf(v.z); o.w = f2bf(v.w);
    *(ushort4*)&dst[i] = o;
  }
}

// ---------------------------------------------------------------------------
// Batched transpose+convert: src f32 [batch][rows][cols] -> dst bf16
// [batch][cols][rows]. grid (cols/32, rows/32, batch), 256 threads.
// ---------------------------------------------------------------------------
__global__ __launch_bounds__(256) void k_tcvt(const float* __restrict__ src,
                                              unsigned short* __restrict__ dst,
                                              int rows, int cols) {
  __shared__ float t[32][33];
  size_t boff = (size_t)blockIdx.z * rows * cols;
  src += boff; dst += boff;
  int c0 = blockIdx.x * 32, r0 = blockIdx.y * 32;
  int tx = threadIdx.x & 31, ty = threadIdx.x >> 5;   // ty 0..7
  for (int i = ty; i < 32; i += 8)
    t[i][tx] = src[(size_t)(r0 + i) * cols + c0 + tx];
  __syncthreads();
  for (int i = ty; i < 32; i += 8)
    dst[(size_t)(c0 + i) * rows + r0 + tx] = f2bf(t[tx][i]);
}

// ---------------------------------------------------------------------------
// Router logits GEMM with FP64 accumulation (exact expert ordering).
// ---------------------------------------------------------------------------
__global__ __launch_bounds__(256) void k_router(
    const float* __restrict__ A, const float* __restrict__ B, float* __restrict__ C) {
  __shared__ float As[32][33];
  __shared__ float Bs[32][64];
  const int m0 = blockIdx.y * 32, n0 = blockIdx.x * 64;
  const int tid = threadIdx.x;
  const int ty = tid >> 4, tx = tid & 15;
  const int lm = tid >> 3;
  const int lk4 = (tid & 7) << 2;

  double acc[2][4] = {{0, 0, 0, 0}, {0, 0, 0, 0}};

  for (int k0 = 0; k0 < Dn; k0 += 32) {
    float4 av = *(const float4*)&A[(size_t)(m0 + lm) * Dn + k0 + lk4];
    As[lk4 + 0][lm] = av.x; As[lk4 + 1][lm] = av.y;
    As[lk4 + 2][lm] = av.z; As[lk4 + 3][lm] = av.w;
#pragma unroll
    for (int q = 0; q < 2; ++q) {
      int idx = tid * 2 + q;
      int br = idx >> 4, bc = (idx & 15) << 2;
      *(float4*)&Bs[br][bc] = *(const float4*)&B[(size_t)(k0 + br) * En + n0 + bc];
    }
    __syncthreads();
#pragma unroll
    for (int kk = 0; kk < 32; ++kk) {
      double a0 = (double)As[kk][ty * 2 + 0];
      double a1 = (double)As[kk][ty * 2 + 1];
      float4 bv = *(const float4*)&Bs[kk][tx << 2];
      acc[0][0] += a0 * (double)bv.x; acc[0][1] += a0 * (double)bv.y;
      acc[0][2] += a0 * (double)bv.z; acc[0][3] += a0 * (double)bv.w;
      acc[1][0] += a1 * (double)bv.x; acc[1][1] += a1 * (double)bv.y;
      acc[1][2] += a1 * (double)bv.z; acc[1][3] += a1 * (double)bv.w;
    }
    __syncthreads();
  }
#pragma unroll
  for (int i = 0; i < 2; ++i) {
    float4 o;
    o.x = (float)acc[i][0]; o.y = (float)acc[i][1];
    o.z = (float)acc[i][2]; o.w = (float)acc[i][3];
    *(float4*)&C[(size_t)(m0 + ty * 2 + i) * En + n0 + (tx << 2)] = o;
  }
}

// ---------------------------------------------------------------------------
// Router top-8: one block per token.
// ---------------------------------------------------------------------------
__global__ __launch_bounds__(256) void k_topk(
    const float* __restrict__ logits, int* __restrict__ sel,
    float* __restrict__ rw, int* __restrict__ cnt_e) {
  int t = blockIdx.x, tid = threadIdx.x;
  __shared__ float pv[256];
  __shared__ float rv[256];
  __shared__ int ri[256];
  __shared__ float topv[8];
  __shared__ int topi[8];
  pv[tid] = logits[(size_t)t * En + tid];
  __syncthreads();
  for (int k = 0; k < 8; ++k) {
    rv[tid] = pv[tid]; ri[tid] = tid;
    __syncthreads();
    for (int s = 128; s > 0; s >>= 1) {
      if (tid < s) {
        float v2 = rv[tid + s]; int i2 = ri[tid + s];
        if (v2 > rv[tid] || (v2 == rv[tid] && i2 < ri[tid])) {
          rv[tid] = v2; ri[tid] = i2;
        }
      }
      __syncthreads();
    }
    if (tid == 0) { topv[k] = rv[0]; topi[k] = ri[0]; pv[ri[0]] = -1e30f; }
    __syncthreads();
  }
  if (tid < 8) {
    float m = topv[0];
    float ssum = 0.f;
#pragma unroll
    for (int k = 0; k < 8; ++k) ssum += expf(topv[k] - m);
    rw[t * 8 + tid] = expf(topv[tid] - m) / ssum;
    sel[t * 8 + tid] = topi[tid];
    atomicAdd(&cnt_e[topi[tid]], 1);
  }
}

__global__ void k_scan(const int* __restrict__ cnt_e, int* __restrict__ off_e,
                       int* __restrict__ cur_e, int* __restrict__ grp_n) {
  if (threadIdx.x == 0 && blockIdx.x == 0) {
    for (int g = 0; g < Gn; ++g) {
      int run = 0;
      for (int ei = 0; ei < EGn; ++ei) {
        int e = g * EGn + ei;
        off_e[e] = g * SEGCAP + run;
        cur_e[e] = g * SEGCAP + run;
        run += cnt_e[e];
      }
      grp_n[g] = run;
    }
  }
}

__global__ void k_scatter(const int* __restrict__ sel, int* __restrict__ cur_e,
                          int* __restrict__ rseg) {
  int i = blockIdx.x * 256 + threadIdx.x;
  int e = sel[i];
  int pos = atomicAdd(&cur_e[e], 1);
  rseg[pos] = i;
}

// ---------------------------------------------------------------------------
// h1[t, g*64+n] = H @ A_fac[g] via MFMA bf16. grid (T0/128, G, 2).
// A-op: Hb bf16 [2048][2048]; B-op: AgT/AuT bf16 [G][R=64][D=2048].
// ---------------------------------------------------------------------------
__global__ __launch_bounds__(256) void k_h1_mfma(
    const unsigned short* __restrict__ Hb,
    const unsigned short* __restrict__ AgT, const unsigned short* __restrict__ AuT,
    float* __restrict__ h1g, float* __restrict__ h1u) {
  const int t0 = blockIdx.x * 128;
  const int g = blockIdx.y;
  const unsigned short* W = (blockIdx.z ? AuT : AgT) + (size_t)g * Rn * Dn;
  float* out = blockIdx.z ? h1u : h1g;

  __shared__ unsigned short As[128 * 72];
  __shared__ unsigned short Bs[64 * 72];
  const int tid = threadIdx.x;
  const int w = tid >> 6, ln = tid & 63;
  const int quad = ln >> 4, lane16 = ln & 15;

  f4v acc[2][4] = {};

  for (int k0 = 0; k0 < Dn; k0 += 64) {
#pragma unroll
    for (int i = 0; i < 4; ++i) {
      int c = tid + i * 256;               // 0..1023, 16B chunks
      int row = c >> 3, cc = (c & 7) * 8;
      *(uint4*)&As[row * 72 + cc] = *(const uint4*)&Hb[(size_t)(t0 + row) * Dn + k0 + cc];
    }
#pragma unroll
    for (int i = 0; i < 2; ++i) {
      int c = tid + i * 256;               // 0..511
      int row = c >> 3, cc = (c & 7) * 8;
      *(uint4*)&Bs[row * 72 + cc] = *(const uint4*)&W[(size_t)row * Dn + k0 + cc];
    }
    __syncthreads();
#pragma unroll
    for (int kk = 0; kk < 2; ++kk) {
      s8v a[2], b[4];
#pragma unroll
      for (int mt = 0; mt < 2; ++mt)
        a[mt] = *(const s8v*)&As[(w * 32 + mt * 16 + lane16) * 72 + kk * 32 + quad * 8];
#pragma unroll
      for (int nt = 0; nt < 4; ++nt)
        b[nt] = *(const s8v*)&Bs[(nt * 16 + lane16) * 72 + kk * 32 + quad * 8];
#pragma unroll
      for (int mt = 0; mt < 2; ++mt)
#pragma unroll
        for (int nt = 0; nt < 4; ++nt)
          acc[mt][nt] = MFMA16(a[mt], b[nt], acc[mt][nt]);
    }
    __syncthreads();
  }
#pragma unroll
  for (int mt = 0; mt < 2; ++mt)
#pragma unroll
    for (int nt = 0; nt < 4; ++nt)
#pragma unroll
      for (int r = 0; r < 4; ++r) {
        int row = t0 + w * 32 + mt * 16 + quad * 4 + r;
        int col = g * 64 + nt * 16 + lane16;
        out[(size_t)row * (Gn * Rn) + col] = acc[mt][nt][r];
      }
}

// ---------------------------------------------------------------------------
// Per-expert core (gate/up), fp32 vector; writes h2 as bf16.
// ---------------------------------------------------------------------------
__global__ __launch_bounds__(256) void k_core_gu(
    const float* __restrict__ h1g, const float* __restrict__ h1u,
    const float* __restrict__ Cgate, const float* __restrict__ Cup,
    const int* __restrict__ rseg, const int* __restrict__ off_e,
    const int* __restrict__ cnt_e,
    unsigned short* __restrict__ h2gb, unsigned short* __restrict__ h2ub) {
  const int e = blockIdx.x;
  const int ne = cnt_e[e];
  if (ne == 0) return;
  const int g = e >> 5;
  const int base = off_e[e];
  __shared__ float Cg[64 * 64];
  __shared__ float Cu[64 * 64];
  __shared__ float Hg[4 * 64];
  __shared__ float Hu[4 * 64];
  const int tid = threadIdx.x;
  {
    const float* cg = Cgate + (size_t)e * (Rn * Rn);
    const float* cu = Cup + (size_t)e * (Rn * Rn);
    int r = tid >> 2, q = (tid & 3) << 4;
#pragma unroll
    for (int i = 0; i < 4; ++i) {
      *(float4*)&Cg[r * 64 + q + i * 4] = *(const float4*)&cg[r * 64 + q + i * 4];
      *(float4*)&Cu[r * 64 + q + i * 4] = *(const float4*)&cu[r * 64 + q + i * 4];
    }
  }
  __syncthreads();
  const int j = tid >> 6, s = tid & 63;
  const int iters = (ne + 3) >> 2;
  for (int it = 0; it < iters; ++it) {
    int mi = (it << 2) + j;
    int rid = (mi < ne) ? rseg[base + mi] : -1;
    Hg[tid] = (rid >= 0) ? h1g[(size_t)(rid >> 3) * (Gn * Rn) + g * Rn + s] : 0.f;
    Hu[tid] = (rid >= 0) ? h1u[(size_t)(rid >> 3) * (Gn * Rn) + g * Rn + s] : 0.f;
    __syncthreads();
    float ag = 0.f, au = 0.f;
#pragma unroll 16
    for (int r = 0; r < 64; ++r) {
      ag += Hg[(j << 6) + r] * Cg[r * 64 + s];
      au += Hu[(j << 6) + r] * Cu[r * 64 + s];
    }
    if (rid >= 0) {
      h2gb[(size_t)rid * 64 + s] = f2bf(ag);
      h2ub[(size_t)rid * 64 + s] = f2bf(au);
    }
    __syncthreads();
  }
}

// ---------------------------------------------------------------------------
// Fused expand + down-A via MFMA, flash-style:
//   Sg = h2g@Bg, Su = h2u@Bu (per 64-col I-chunk), inter = silu(Sg)*Su
//   round-trips LDS as bf16 (C-layout -> A-layout), P += inter @ Ad_chunk.
// grid (4 I-splits, NROWS/64 row tiles, G). Non-working blocks exit early.
// ---------------------------------------------------------------------------
__global__ __launch_bounds__(256) void k_expand_mfma(
    const unsigned short* __restrict__ h2gb, const unsigned short* __restrict__ h2ub,
    const unsigned short* __restrict__ BgT, const unsigned short* __restrict__ BuT,
    const unsigned short* __restrict__ AdT,
    const int* __restrict__ rseg, const int* __restrict__ grp_n,
    float* __restrict__ h1d) {
  const int g = blockIdx.z;
  const int ng = grp_n[g];
  const int m0 = blockIdx.y * 64;
  if (m0 >= ng) return;
  const int c_beg = blockIdx.x * 6;
  const int c_end = min(22, c_beg + 6);

  __shared__ unsigned short Hg_l[64 * 72];
  __shared__ unsigned short Hu_l[64 * 72];
  __shared__ unsigned short Bg_l[64 * 72];   // aliased as inter after Sg/Su
  __shared__ unsigned short Bu_l[64 * 72];
  __shared__ unsigned short Ad_l[64 * 72];
  __shared__ int rids[64];

  const int tid = threadIdx.x;
  const int w = tid >> 6, ln = tid & 63;
  const int quad = ln >> 4, lane16 = ln & 15;

  if (tid < 64) rids[tid] = (m0 + tid < ng) ? rseg[g * SEGCAP + m0 + tid] : -1;
  __syncthreads();
#pragma unroll
  for (int i = 0; i < 2; ++i) {
    int c = tid + i * 256;
    int row = c >> 3, cc = (c & 7) * 8;
    int rid = rids[row];
    uint4 zg = {0, 0, 0, 0}, zu = {0, 0, 0, 0};
    if (rid >= 0) {
      zg = *(const uint4*)&h2gb[(size_t)rid * 64 + cc];
      zu = *(const uint4*)&h2ub[(size_t)rid * 64 + cc];
    }
    *(uint4*)&Hg_l[row * 72 + cc] = zg;
    *(uint4*)&Hu_l[row * 72 + cc] = zu;
  }

  const unsigned short* Bg_base = BgT + (size_t)g * In * Rn;   // [I][R]
  const unsigned short* Bu_base = BuT + (size_t)g * In * Rn;   // [I][R]
  const unsigned short* Ad_base = AdT + (size_t)g * Rn * In;   // [R][I]

  f4v P[4] = {};

  for (int c = c_beg; c < c_end; ++c) {
    const int i0 = c * 64;
#pragma unroll
    for (int i = 0; i < 2; ++i) {
      int cq = tid + i * 256;
      int row = cq >> 3, co = (cq & 7) * 8;
      *(uint4*)&Bg_l[row * 72 + co] = *(const uint4*)&Bg_base[(size_t)(i0 + row) * Rn + co];
      *(uint4*)&Bu_l[row * 72 + co] = *(const uint4*)&Bu_base[(size_t)(i0 + row) * Rn + co];
      *(uint4*)&Ad_l[row * 72 + co] = *(const uint4*)&Ad_base[(size_t)row * In + i0 + co];
    }
    __syncthreads();

    f4v Sg[4] = {}, Su[4] = {};
#pragma unroll
    for (int kk = 0; kk < 2; ++kk) {
      s8v ag = *(const s8v*)&Hg_l[(w * 16 + lane16) * 72 + kk * 32 + quad * 8];
      s8v au = *(const s8v*)&Hu_l[(w * 16 + lane16) * 72 + kk * 32 + quad * 8];
#pragma unroll
      for (int nt = 0; nt < 4; ++nt) {
        s8v bg = *(const s8v*)&Bg_l[(nt * 16 + lane16) * 72 + kk * 32 + quad * 8];
        s8v bu = *(const s8v*)&Bu_l[(nt * 16 + lane16) * 72 + kk * 32 + quad * 8];
        Sg[nt] = MFMA16(ag, bg, Sg[nt]);
        Su[nt] = MFMA16(au, bu, Su[nt]);
      }
    }
    __syncthreads();   // all Bg_l reads done before overwrite as inter
#pragma unroll
    for (int nt = 0; nt < 4; ++nt)
#pragma unroll
      for (int r = 0; r < 4; ++r) {
        float sg = Sg[nt][r];
        float v = sg / (1.f + __expf(-sg)) * Su[nt][r];
        Bg_l[(w * 16 + quad * 4 + r) * 72 + nt * 16 + lane16] = f2bf(v);
      }
    __syncthreads();
#pragma unroll
    for (int kk = 0; kk < 2; ++kk) {
      s8v ai = *(const s8v*)&Bg_l[(w * 16 + lane16) * 72 + kk * 32 + quad * 8];
#pragma unroll
      for (int nt = 0; nt < 4; ++nt) {
        s8v bd = *(const s8v*)&Ad_l[(nt * 16 + lane16) * 72 + kk * 32 + quad * 8];
        P[nt] = MFMA16(ai, bd, P[nt]);
      }
    }
    __syncthreads();   // before next chunk restages Bg_l/Bu_l/Ad_l
  }

#pragma unroll
  for (int nt = 0; nt < 4; ++nt)
#pragma unroll
    for (int r = 0; r < 4; ++r) {
      int lrow = w * 16 + quad * 4 + r;
      int rid = rids[lrow];
      if (rid >= 0)
        atomicAdd(&h1d[(size_t)rid * 64 + nt * 16 + lane16], P[nt][r]);
    }
}

// ---------------------------------------------------------------------------
// Per-expert down core + routing weight, fp32 vector, reduce to y[t,g,64].
// ---------------------------------------------------------------------------
__global__ __launch_bounds__(256) void k_core_down(
    const float* __restrict__ h1d, const float* __restrict__ Cdown,
    const float* __restrict__ rw,
    const int* __restrict__ rseg, const int* __restrict__ off_e,
    const int* __restrict__ cnt_e,
    float* __restrict__ y) {
  const int e = blockIdx.x;
  const int ne = cnt_e[e];
  if (ne == 0) return;
  const int g = e >> 5;
  const int base = off_e[e];
  __shared__ float Cd[64 * 64];
  __shared__ float Hd[4 * 64];
  const int tid = threadIdx.x;
  {
    const float* cd = Cdown + (size_t)e * (Rn * Rn);
    int r = tid >> 2, q = (tid & 3) << 4;
#pragma unroll
    for (int i = 0; i < 4; ++i)
      *(float4*)&Cd[r * 64 + q + i * 4] = *(const float4*)&cd[r * 64 + q + i * 4];
  }
  __syncthreads();
  const int j = tid >> 6, s = tid & 63;
  const int iters = (ne + 3) >> 2;
  for (int it = 0; it < iters; ++it) {
    int mi = (it << 2) + j;
    int rid = (mi < ne) ? rseg[base + mi] : -1;
    Hd[tid] = (rid >= 0) ? h1d[(size_t)rid * 64 + s] : 0.f;
    __syncthreads();
    float a = 0.f;
#pragma unroll 16
    for (int r = 0; r < 64; ++r)
      a += Hd[(j << 6) + r] * Cd[r * 64 + s];
    if (rid >= 0) {
      float wgt = rw[rid];
      atomicAdd(&y[(size_t)(rid >> 3) * (Gn * Rn) + g * Rn + s], wgt * a);
    }
    __syncthreads();
  }
}

// ---------------------------------------------------------------------------
// Combine: out[2048,2048] = y[2048,512] @ B_down-as-[512,2048], MFMA bf16.
// A staged with on-the-fly f32->bf16; B-op from BdT bf16 [2048][512].
// grid (16, 16), 128x128 tiles, 4 waves of 64x64.
// ---------------------------------------------------------------------------
__global__ __launch_bounds__(256) void k_combine(
    const float* __restrict__ y, const unsigned short* __restrict__ BdT,
    float* __restrict__ outp) {
  const int t0 = blockIdx.y * 128, n0 = blockIdx.x * 128;
  __shared__ unsigned short As[128 * 72];
  __shared__ unsigned short Bs[128 * 72];
  const int tid = threadIdx.x;
  const int w = tid >> 6, ln = tid & 63;
  const int quad = ln >> 4, lane16 = ln & 15;
  const int mbase = (w >> 1) * 64, nbase = (w & 1) * 64;

  f4v acc[4][4] = {};

  for (int k0 = 0; k0 < Gn * Rn; k0 += 64) {
#pragma unroll
    for (int i = 0; i < 8; ++i) {
      int c = tid + i * 256;               // float4 chunk 0..2047
      int row = c >> 4, cc = (c & 15) * 4;
      float4 v = *(const float4*)&y[(size_t)(t0 + row) * (Gn * Rn) + k0 + cc];
      ushort4 o;
      o.x = f2bf(v.x); o.y = f2bf(v.y); o.z = f2bf(v.z); o.w = f2bf(v.w);
      *(ushort4*)&As[row * 72 + cc] = o;
    }
#pragma unroll
    for (int i = 0; i < 4; ++i) {
      int c = tid + i * 256;               // 16B chunk 0..1023
      int row = c >> 3, cc = (c & 7) * 8;
      *(uint4*)&Bs[row * 72 + cc] = *(const uint4*)&BdT[(size_t)(n0 + row) * (Gn * Rn) + k0 + cc];
    }
    __syncthreads();
#pragma unroll
    for (int kk = 0; kk < 2; ++kk) {
      s8v a[4], b[4];
#pragma unroll
      for (int mt = 0; mt < 4; ++mt)
        a[mt] = *(const s8v*)&As[(mbase + mt * 16 + lane16) * 72 + kk * 32 + quad * 8];
#pragma unroll
      for (int nt = 0; nt < 4; ++nt)
        b[nt] = *(const s8v*)&Bs[(nbase + nt * 16 + lane16) * 72 + kk * 32 + quad * 8];
#pragma unroll
      for (int mt = 0; mt < 4; ++mt)
#pragma unroll
        for (int nt = 0; nt < 4; ++nt)
          acc[mt][nt] = MFMA16(a[mt], b[nt], acc[mt][nt]);
    }
    __syncthreads();
  }
#pragma unroll
  for (int mt = 0; mt < 4; ++mt)
#pragma unroll
    for (int nt = 0; nt < 4; ++nt)
#pragma unroll
      for (int r = 0; r < 4; ++r)
        outp[(size_t)(t0 + mbase + mt * 16 + quad * 4 + r) * Dn +
             n0 + nbase + nt * 16 + lane16] = acc[mt][nt][r];
}

// ---------------------------------------------------------------------------
extern "C" void kernel_launch(void* const* d_in, const int* in_sizes, int n_in,
                              void* d_out, int out_size, void* d_ws, size_t ws_size,
                              hipStream_t stream) {
  const float* hidden = (const float*)d_in[0];
  const float* w_gate = (const float*)d_in[1];
  const float* A_gate = (const float*)d_in[2];
  const float* C_gate = (const float*)d_in[3];
  const float* B_gate = (const float*)d_in[4];
  const float* A_up   = (const float*)d_in[5];
  const float* C_up   = (const float*)d_in[6];
  const float* B_up   = (const float*)d_in[7];
  const float* A_down = (const float*)d_in[8];
  const float* C_down = (const float*)d_in[9];
  const float* B_down = (const float*)d_in[10];
  float* out = (float*)d_out;

  // fp32 region
  float* ws     = (float*)d_ws;
  float* logits = ws;                          // 524288
  float* h1g    = logits + (size_t)T0n * En;   // 1048576
  float* h1u    = h1g + (size_t)T0n * Gn * Rn;
  float* h1d    = h1u + (size_t)T0n * Gn * Rn; // 1048576 (zeroed)
  float* y      = h1d + (size_t)NROWS * Rn;    // 1048576 (zeroed)
  float* rwp    = y + (size_t)T0n * Gn * Rn;   // 16384
  int* sel   = (int*)(rwp + NROWS);            // 16384
  int* rseg  = sel + NROWS;                    // 131072
  int* cnt_e = rseg + Gn * SEGCAP;             // 256
  int* off_e = cnt_e + En;
  int* cur_e = off_e + En;
  int* grp_n = cur_e + En;
  // bf16 region
  unsigned short* Hb   = (unsigned short*)(grp_n + Gn + 8);
  unsigned short* h2gb = Hb + (size_t)T0n * Dn;          // 1048576
  unsigned short* h2ub = h2gb + (size_t)NROWS * Rn;
  unsigned short* AgT  = h2ub + (size_t)NROWS * Rn;      // [G][R][D]
  unsigned short* AuT  = AgT + (size_t)Gn * Rn * Dn;
  unsigned short* BgT  = AuT + (size_t)Gn * Rn * Dn;     // [G][I][R]
  unsigned short* BuT  = BgT + (size_t)Gn * In * Rn;
  unsigned short* AdT  = BuT + (size_t)Gn * In * Rn;     // [G][R][I]
  unsigned short* BdT  = AdT + (size_t)Gn * Rn * In;     // [D][G*R]

  hipMemsetAsync(h1d, 0, (size_t)NROWS * Rn * sizeof(float), stream);
  hipMemsetAsync(y,   0, (size_t)T0n * Gn * Rn * sizeof(float), stream);
  hipMemsetAsync(cnt_e, 0, En * sizeof(int), stream);

  // 0) conversions / transposes to bf16 operand layouts
  k_cvt<<<(T0n * Dn) / 1024, 256, 0, stream>>>(hidden, Hb, T0n * Dn);
  k_tcvt<<<dim3(Rn / 32, Dn / 32, Gn), 256, 0, stream>>>(A_gate, AgT, Dn, Rn);
  k_tcvt<<<dim3(Rn / 32, Dn / 32, Gn), 256, 0, stream>>>(A_up,   AuT, Dn, Rn);
  k_tcvt<<<dim3(In / 32, Rn / 32, Gn), 256, 0, stream>>>(B_gate, BgT, Rn, In);
  k_tcvt<<<dim3(In / 32, Rn / 32, Gn), 256, 0, stream>>>(B_up,   BuT, Rn, In);
  k_tcvt<<<dim3(Rn / 32, In / 32, Gn), 256, 0, stream>>>(A_down, AdT, In, Rn);
  k_tcvt<<<dim3(Dn / 32, (Gn * Rn) / 32, 1), 256, 0, stream>>>(B_down, BdT, Gn * Rn, Dn);

  // 1) router logits (fp64 accumulation -> exact expert ordering)
  k_router<<<dim3(En / 64, T0n / 32), 256, 0, stream>>>(hidden, w_gate, logits);
  // 2) dense in-factor projections (MFMA bf16)
  k_h1_mfma<<<dim3(T0n / 128, Gn, 2), 256, 0, stream>>>(Hb, AgT, AuT, h1g, h1u);
  // 3) top-8 + renorm + expert counts
  k_topk<<<T0n, 256, 0, stream>>>(logits, sel, rwp, cnt_e);
  // 4) offsets + scatter rows by expert (expert-major => group-major)
  k_scan<<<1, 64, 0, stream>>>(cnt_e, off_e, cur_e, grp_n);
  k_scatter<<<NROWS / 256, 256, 0, stream>>>(sel, cur_e, rseg);
  // 5) per-expert core (gate/up), h2 out in bf16
  k_core_gu<<<En, 256, 0, stream>>>(h1g, h1u, C_gate, C_up,
                                    rseg, off_e, cnt_e, h2gb, h2ub);
  // 6) fused expand + down-A (MFMA; inter stays on-chip)
  k_expand_mfma<<<dim3(4, NROWS / 64, Gn), 256, 0, stream>>>(
      h2gb, h2ub, BgT, BuT, AdT, rseg, grp_n, h1d);
  // 7) per-expert down core + rw, reduce to y[t,g,:]
  k_core_down<<<En, 256, 0, stream>>>(h1d, C_down, rwp,
                                      rseg, off_e, cnt_e, y);
  // 8) combine (MFMA bf16)
  k_combine<<<dim3(Dn / 128, T0n / 128), 256, 0, stream>>>(y, BdT, out);
}

// Round 4
// 452.879 us; speedup vs baseline: 1.8478x; 1.1843x over previous
//
#include <hip/hip_runtime.h>
#include <math.h>

// Problem dims
constexpr int T0n = 2048;   // tokens
constexpr int Dn  = 2048;   // hidden
constexpr int En  = 256;    // experts
constexpr int Gn  = 8;      // groups
constexpr int EGn = 32;     // experts per group
constexpr int Rn  = 64;     // tucker rank
constexpr int In  = 1408;   // intermediate

constexpr int NROWS = T0n * 8;    // 16384 dispatched rows
constexpr int SEGCAP = NROWS;     // per-group segment capacity in rseg
constexpr int KSPLIT = 4;         // router split-K factor

typedef __attribute__((ext_vector_type(8))) short s8v;   // 8 bf16
typedef __attribute__((ext_vector_type(4))) float f4v;   // 4 fp32
#define MFMA16(a, b, c) __builtin_amdgcn_mfma_f32_16x16x32_bf16(a, b, c, 0, 0, 0)

__device__ __forceinline__ unsigned short f2bf(float x) {
  unsigned int u = __float_as_uint(x);
  unsigned int r = (u + 0x7FFFu + ((u >> 16) & 1u)) >> 16;
  return (unsigned short)r;
}

// ---------------------------------------------------------------------------
// fp32 -> bf16 elementwise (n multiple of 1024)
// ---------------------------------------------------------------------------
__global__ __launch_bounds__(256) void k_cvt(const float* __restrict__ src,
                                             unsigned short* __restrict__ dst, int n) {
  int i = (blockIdx.x * 256 + threadIdx.x) * 4;
  if (i < n) {
    float4 v = *(const float4*)&src[i];
    ushort4 o;
    o.x = f2bf(v.x); o.y = f2bf(v.y); o.z = f2bf(v.z); o.w = f2bf(v.w);
    *(ushort4*)&dst[i] = o;
  }
}

// ---------------------------------------------------------------------------
// Fused batched transpose+convert for all 6 weight tensors:
// src f32 [batch][rows][cols] -> dst bf16 [batch][cols][rows].
// One launch; block -> (tensor, bz, by, bx) via descriptor table.
// ---------------------------------------------------------------------------
struct TD { const float* src; unsigned short* dst; int rows, cols, nbx, per_batch, base; };
struct TD6 { TD t[6]; };

__global__ __launch_bounds__(256) void k_tcvt6(TD6 D) {
  __shared__ float tbuf[32][33];
  int id = blockIdx.x;
  int ti = 0;
#pragma unroll
  for (int i = 1; i < 6; ++i) ti = (id >= D.t[i].base) ? i : ti;
  TD d = D.t[ti];
  int local = id - d.base;
  int bz = local / d.per_batch;
  int rem = local - bz * d.per_batch;
  int by = rem / d.nbx;
  int bx = rem - by * d.nbx;

  size_t boff = (size_t)bz * d.rows * d.cols;
  const float* src = d.src + boff;
  unsigned short* dst = d.dst + boff;
  int c0 = bx * 32, r0 = by * 32;
  int tx = threadIdx.x & 31, ty = threadIdx.x >> 5;   // ty 0..7
  for (int i = ty; i < 32; i += 8)
    tbuf[i][tx] = src[(size_t)(r0 + i) * d.cols + c0 + tx];
  __syncthreads();
  for (int i = ty; i < 32; i += 8)
    dst[(size_t)(c0 + i) * d.rows + r0 + tx] = f2bf(tbuf[tx][i]);
}

// ---------------------------------------------------------------------------
// Router logits, split-K with FP64 accumulation (exact expert ordering).
// part[kc][t][e] fp64 partials; grid (E/64, T0/32, KSPLIT).
// ---------------------------------------------------------------------------
__global__ __launch_bounds__(256) void k_router_part(
    const float* __restrict__ A, const float* __restrict__ B,
    double* __restrict__ part) {
  __shared__ float As[32][33];
  __shared__ float Bs[32][64];
  const int m0 = blockIdx.y * 32, n0 = blockIdx.x * 64;
  const int kc = blockIdx.z;
  const int kbeg = kc * (Dn / KSPLIT), kend = kbeg + Dn / KSPLIT;
  const int tid = threadIdx.x;
  const int ty = tid >> 4, tx = tid & 15;
  const int lm = tid >> 3;
  const int lk4 = (tid & 7) << 2;

  double acc[2][4] = {{0, 0, 0, 0}, {0, 0, 0, 0}};

  for (int k0 = kbeg; k0 < kend; k0 += 32) {
    float4 av = *(const float4*)&A[(size_t)(m0 + lm) * Dn + k0 + lk4];
    As[lk4 + 0][lm] = av.x; As[lk4 + 1][lm] = av.y;
    As[lk4 + 2][lm] = av.z; As[lk4 + 3][lm] = av.w;
#pragma unroll
    for (int q = 0; q < 2; ++q) {
      int idx = tid * 2 + q;
      int br = idx >> 4, bc = (idx & 15) << 2;
      *(float4*)&Bs[br][bc] = *(const float4*)&B[(size_t)(k0 + br) * En + n0 + bc];
    }
    __syncthreads();
#pragma unroll
    for (int kk = 0; kk < 32; ++kk) {
      double a0 = (double)As[kk][ty * 2 + 0];
      double a1 = (double)As[kk][ty * 2 + 1];
      float4 bv = *(const float4*)&Bs[kk][tx << 2];
      acc[0][0] += a0 * (double)bv.x; acc[0][1] += a0 * (double)bv.y;
      acc[0][2] += a0 * (double)bv.z; acc[0][3] += a0 * (double)bv.w;
      acc[1][0] += a1 * (double)bv.x; acc[1][1] += a1 * (double)bv.y;
      acc[1][2] += a1 * (double)bv.z; acc[1][3] += a1 * (double)bv.w;
    }
    __syncthreads();
  }
  double* prow = part + (size_t)kc * T0n * En;
#pragma unroll
  for (int i = 0; i < 2; ++i) {
#pragma unroll
    for (int jj = 0; jj < 4; ++jj)
      prow[(size_t)(m0 + ty * 2 + i) * En + n0 + (tx << 2) + jj] = acc[i][jj];
  }
}

// ---------------------------------------------------------------------------
// Top-8: one wave per token, shuffle butterfly (no barriers). Sums the
// KSPLIT fp64 partials -> exact fp64 ordering. Lane ln owns experts ln+64j.
// ---------------------------------------------------------------------------
__global__ __launch_bounds__(256) void k_topk(
    const double* __restrict__ part, int* __restrict__ sel,
    float* __restrict__ rw, int* __restrict__ cnt_e) {
  const int wid = threadIdx.x >> 6, ln = threadIdx.x & 63;
  const int t = blockIdx.x * 4 + wid;

  double v[4];
#pragma unroll
  for (int j = 0; j < 4; ++j) {
    double s = 0.0;
#pragma unroll
    for (int kc = 0; kc < KSPLIT; ++kc)
      s += part[((size_t)kc * T0n + t) * En + ln + 64 * j];
    v[j] = s;
  }

  float topv[8];
  int topi[8];
#pragma unroll
  for (int k = 0; k < 8; ++k) {
    double bv = v[0]; int bi = ln;
#pragma unroll
    for (int j = 1; j < 4; ++j) {
      int cand = ln + 64 * j;
      if (v[j] > bv || (v[j] == bv && cand < bi)) { bv = v[j]; bi = cand; }
    }
#pragma unroll
    for (int off = 32; off > 0; off >>= 1) {
      double ov = __shfl_xor(bv, off);
      int oi = __shfl_xor(bi, off);
      if (ov > bv || (ov == bv && oi < bi)) { bv = ov; bi = oi; }
    }
    topv[k] = (float)bv; topi[k] = bi;
    if ((bi & 63) == ln) v[bi >> 6] = -1e300;
  }

  if (ln < 8) {
    float m = topv[0];
    float ssum = 0.f;
#pragma unroll
    for (int k = 0; k < 8; ++k) ssum += expf(topv[k] - m);
    rw[t * 8 + ln] = expf(topv[ln] - m) / ssum;
    sel[t * 8 + ln] = topi[ln];
    atomicAdd(&cnt_e[topi[ln]], 1);
  }
}

__global__ void k_scan(const int* __restrict__ cnt_e, int* __restrict__ off_e,
                       int* __restrict__ cur_e, int* __restrict__ grp_n) {
  if (threadIdx.x == 0 && blockIdx.x == 0) {
    for (int g = 0; g < Gn; ++g) {
      int run = 0;
      for (int ei = 0; ei < EGn; ++ei) {
        int e = g * EGn + ei;
        off_e[e] = g * SEGCAP + run;
        cur_e[e] = g * SEGCAP + run;
        run += cnt_e[e];
      }
      grp_n[g] = run;
    }
  }
}

__global__ void k_scatter(const int* __restrict__ sel, int* __restrict__ cur_e,
                          int* __restrict__ rseg) {
  int i = blockIdx.x * 256 + threadIdx.x;
  int e = sel[i];
  int pos = atomicAdd(&cur_e[e], 1);
  rseg[pos] = i;
}

// ---------------------------------------------------------------------------
// h1[t, g*64+n] = H @ A_fac[g] via MFMA bf16. grid (T0/128, G, 2).
// ---------------------------------------------------------------------------
__global__ __launch_bounds__(256) void k_h1_mfma(
    const unsigned short* __restrict__ Hb,
    const unsigned short* __restrict__ AgT, const unsigned short* __restrict__ AuT,
    float* __restrict__ h1g, float* __restrict__ h1u) {
  const int t0 = blockIdx.x * 128;
  const int g = blockIdx.y;
  const unsigned short* W = (blockIdx.z ? AuT : AgT) + (size_t)g * Rn * Dn;
  float* out = blockIdx.z ? h1u : h1g;

  __shared__ unsigned short As[128 * 72];
  __shared__ unsigned short Bs[64 * 72];
  const int tid = threadIdx.x;
  const int w = tid >> 6, ln = tid & 63;
  const int quad = ln >> 4, lane16 = ln & 15;

  f4v acc[2][4] = {};

  for (int k0 = 0; k0 < Dn; k0 += 64) {
#pragma unroll
    for (int i = 0; i < 4; ++i) {
      int c = tid + i * 256;
      int row = c >> 3, cc = (c & 7) * 8;
      *(uint4*)&As[row * 72 + cc] = *(const uint4*)&Hb[(size_t)(t0 + row) * Dn + k0 + cc];
    }
#pragma unroll
    for (int i = 0; i < 2; ++i) {
      int c = tid + i * 256;
      int row = c >> 3, cc = (c & 7) * 8;
      *(uint4*)&Bs[row * 72 + cc] = *(const uint4*)&W[(size_t)row * Dn + k0 + cc];
    }
    __syncthreads();
#pragma unroll
    for (int kk = 0; kk < 2; ++kk) {
      s8v a[2], b[4];
#pragma unroll
      for (int mt = 0; mt < 2; ++mt)
        a[mt] = *(const s8v*)&As[(w * 32 + mt * 16 + lane16) * 72 + kk * 32 + quad * 8];
#pragma unroll
      for (int nt = 0; nt < 4; ++nt)
        b[nt] = *(const s8v*)&Bs[(nt * 16 + lane16) * 72 + kk * 32 + quad * 8];
#pragma unroll
      for (int mt = 0; mt < 2; ++mt)
#pragma unroll
        for (int nt = 0; nt < 4; ++nt)
          acc[mt][nt] = MFMA16(a[mt], b[nt], acc[mt][nt]);
    }
    __syncthreads();
  }
#pragma unroll
  for (int mt = 0; mt < 2; ++mt)
#pragma unroll
    for (int nt = 0; nt < 4; ++nt)
#pragma unroll
      for (int r = 0; r < 4; ++r) {
        int row = t0 + w * 32 + mt * 16 + quad * 4 + r;
        int col = g * 64 + nt * 16 + lane16;
        out[(size_t)row * (Gn * Rn) + col] = acc[mt][nt][r];
      }
}

// ---------------------------------------------------------------------------
// Per-expert core (gate/up), fp32 vector; writes h2 as bf16.
// ---------------------------------------------------------------------------
__global__ __launch_bounds__(256) void k_core_gu(
    const float* __restrict__ h1g, const float* __restrict__ h1u,
    const float* __restrict__ Cgate, const float* __restrict__ Cup,
    const int* __restrict__ rseg, const int* __restrict__ off_e,
    const int* __restrict__ cnt_e,
    unsigned short* __restrict__ h2gb, unsigned short* __restrict__ h2ub) {
  const int e = blockIdx.x;
  const int ne = cnt_e[e];
  if (ne == 0) return;
  const int g = e >> 5;
  const int base = off_e[e];
  __shared__ float Cg[64 * 64];
  __shared__ float Cu[64 * 64];
  __shared__ float Hg[4 * 64];
  __shared__ float Hu[4 * 64];
  const int tid = threadIdx.x;
  {
    const float* cg = Cgate + (size_t)e * (Rn * Rn);
    const float* cu = Cup + (size_t)e * (Rn * Rn);
    int r = tid >> 2, q = (tid & 3) << 4;
#pragma unroll
    for (int i = 0; i < 4; ++i) {
      *(float4*)&Cg[r * 64 + q + i * 4] = *(const float4*)&cg[r * 64 + q + i * 4];
      *(float4*)&Cu[r * 64 + q + i * 4] = *(const float4*)&cu[r * 64 + q + i * 4];
    }
  }
  __syncthreads();
  const int j = tid >> 6, s = tid & 63;
  const int iters = (ne + 3) >> 2;
  for (int it = 0; it < iters; ++it) {
    int mi = (it << 2) + j;
    int rid = (mi < ne) ? rseg[base + mi] : -1;
    Hg[tid] = (rid >= 0) ? h1g[(size_t)(rid >> 3) * (Gn * Rn) + g * Rn + s] : 0.f;
    Hu[tid] = (rid >= 0) ? h1u[(size_t)(rid >> 3) * (Gn * Rn) + g * Rn + s] : 0.f;
    __syncthreads();
    float ag = 0.f, au = 0.f;
#pragma unroll 16
    for (int r = 0; r < 64; ++r) {
      ag += Hg[(j << 6) + r] * Cg[r * 64 + s];
      au += Hu[(j << 6) + r] * Cu[r * 64 + s];
    }
    if (rid >= 0) {
      h2gb[(size_t)rid * 64 + s] = f2bf(ag);
      h2ub[(size_t)rid * 64 + s] = f2bf(au);
    }
    __syncthreads();
  }
}

// ---------------------------------------------------------------------------
// Fused expand + down-A via MFMA (inter stays on-chip).
// grid (4 I-splits, NROWS/64 row tiles, G).
// ---------------------------------------------------------------------------
__global__ __launch_bounds__(256) void k_expand_mfma(
    const unsigned short* __restrict__ h2gb, const unsigned short* __restrict__ h2ub,
    const unsigned short* __restrict__ BgT, const unsigned short* __restrict__ BuT,
    const unsigned short* __restrict__ AdT,
    const int* __restrict__ rseg, const int* __restrict__ grp_n,
    float* __restrict__ h1d) {
  const int g = blockIdx.z;
  const int ng = grp_n[g];
  const int m0 = blockIdx.y * 64;
  if (m0 >= ng) return;
  const int c_beg = blockIdx.x * 6;
  const int c_end = min(22, c_beg + 6);

  __shared__ unsigned short Hg_l[64 * 72];
  __shared__ unsigned short Hu_l[64 * 72];
  __shared__ unsigned short Bg_l[64 * 72];
  __shared__ unsigned short Bu_l[64 * 72];
  __shared__ unsigned short Ad_l[64 * 72];
  __shared__ int rids[64];

  const int tid = threadIdx.x;
  const int w = tid >> 6, ln = tid & 63;
  const int quad = ln >> 4, lane16 = ln & 15;

  if (tid < 64) rids[tid] = (m0 + tid < ng) ? rseg[g * SEGCAP + m0 + tid] : -1;
  __syncthreads();
#pragma unroll
  for (int i = 0; i < 2; ++i) {
    int c = tid + i * 256;
    int row = c >> 3, cc = (c & 7) * 8;
    int rid = rids[row];
    uint4 zg = {0, 0, 0, 0}, zu = {0, 0, 0, 0};
    if (rid >= 0) {
      zg = *(const uint4*)&h2gb[(size_t)rid * 64 + cc];
      zu = *(const uint4*)&h2ub[(size_t)rid * 64 + cc];
    }
    *(uint4*)&Hg_l[row * 72 + cc] = zg;
    *(uint4*)&Hu_l[row * 72 + cc] = zu;
  }

  const unsigned short* Bg_base = BgT + (size_t)g * In * Rn;
  const unsigned short* Bu_base = BuT + (size_t)g * In * Rn;
  const unsigned short* Ad_base = AdT + (size_t)g * Rn * In;

  f4v P[4] = {};

  for (int c = c_beg; c < c_end; ++c) {
    const int i0 = c * 64;
#pragma unroll
    for (int i = 0; i < 2; ++i) {
      int cq = tid + i * 256;
      int row = cq >> 3, co = (cq & 7) * 8;
      *(uint4*)&Bg_l[row * 72 + co] = *(const uint4*)&Bg_base[(size_t)(i0 + row) * Rn + co];
      *(uint4*)&Bu_l[row * 72 + co] = *(const uint4*)&Bu_base[(size_t)(i0 + row) * Rn + co];
      *(uint4*)&Ad_l[row * 72 + co] = *(const uint4*)&Ad_base[(size_t)row * In + i0 + co];
    }
    __syncthreads();

    f4v Sg[4] = {}, Su[4] = {};
#pragma unroll
    for (int kk = 0; kk < 2; ++kk) {
      s8v ag = *(const s8v*)&Hg_l[(w * 16 + lane16) * 72 + kk * 32 + quad * 8];
      s8v au = *(const s8v*)&Hu_l[(w * 16 + lane16) * 72 + kk * 32 + quad * 8];
#pragma unroll
      for (int nt = 0; nt < 4; ++nt) {
        s8v bg = *(const s8v*)&Bg_l[(nt * 16 + lane16) * 72 + kk * 32 + quad * 8];
        s8v bu = *(const s8v*)&Bu_l[(nt * 16 + lane16) * 72 + kk * 32 + quad * 8];
        Sg[nt] = MFMA16(ag, bg, Sg[nt]);
        Su[nt] = MFMA16(au, bu, Su[nt]);
      }
    }
    __syncthreads();
#pragma unroll
    for (int nt = 0; nt < 4; ++nt)
#pragma unroll
      for (int r = 0; r < 4; ++r) {
        float sg = Sg[nt][r];
        float v = sg / (1.f + __expf(-sg)) * Su[nt][r];
        Bg_l[(w * 16 + quad * 4 + r) * 72 + nt * 16 + lane16] = f2bf(v);
      }
    __syncthreads();
#pragma unroll
    for (int kk = 0; kk < 2; ++kk) {
      s8v ai = *(const s8v*)&Bg_l[(w * 16 + lane16) * 72 + kk * 32 + quad * 8];
#pragma unroll
      for (int nt = 0; nt < 4; ++nt) {
        s8v bd = *(const s8v*)&Ad_l[(nt * 16 + lane16) * 72 + kk * 32 + quad * 8];
        P[nt] = MFMA16(ai, bd, P[nt]);
      }
    }
    __syncthreads();
  }

#pragma unroll
  for (int nt = 0; nt < 4; ++nt)
#pragma unroll
    for (int r = 0; r < 4; ++r) {
      int lrow = w * 16 + quad * 4 + r;
      int rid = rids[lrow];
      if (rid >= 0)
        atomicAdd(&h1d[(size_t)rid * 64 + nt * 16 + lane16], P[nt][r]);
    }
}

// ---------------------------------------------------------------------------
// Per-expert down core + routing weight, fp32 vector, reduce to y[t,g,64].
// ---------------------------------------------------------------------------
__global__ __launch_bounds__(256) void k_core_down(
    const float* __restrict__ h1d, const float* __restrict__ Cdown,
    const float* __restrict__ rw,
    const int* __restrict__ rseg, const int* __restrict__ off_e,
    const int* __restrict__ cnt_e,
    float* __restrict__ y) {
  const int e = blockIdx.x;
  const int ne = cnt_e[e];
  if (ne == 0) return;
  const int g = e >> 5;
  const int base = off_e[e];
  __shared__ float Cd[64 * 64];
  __shared__ float Hd[4 * 64];
  const int tid = threadIdx.x;
  {
    const float* cd = Cdown + (size_t)e * (Rn * Rn);
    int r = tid >> 2, q = (tid & 3) << 4;
#pragma unroll
    for (int i = 0; i < 4; ++i)
      *(float4*)&Cd[r * 64 + q + i * 4] = *(const float4*)&cd[r * 64 + q + i * 4];
  }
  __syncthreads();
  const int j = tid >> 6, s = tid & 63;
  const int iters = (ne + 3) >> 2;
  for (int it = 0; it < iters; ++it) {
    int mi = (it << 2) + j;
    int rid = (mi < ne) ? rseg[base + mi] : -1;
    Hd[tid] = (rid >= 0) ? h1d[(size_t)rid * 64 + s] : 0.f;
    __syncthreads();
    float a = 0.f;
#pragma unroll 16
    for (int r = 0; r < 64; ++r)
      a += Hd[(j << 6) + r] * Cd[r * 64 + s];
    if (rid >= 0) {
      float wgt = rw[rid];
      atomicAdd(&y[(size_t)(rid >> 3) * (Gn * Rn) + g * Rn + s], wgt * a);
    }
    __syncthreads();
  }
}

// ---------------------------------------------------------------------------
// Combine: out[2048,2048] = y[2048,512] @ B_down-as-[512,2048], MFMA bf16.
// ---------------------------------------------------------------------------
__global__ __launch_bounds__(256) void k_combine(
    const float* __restrict__ y, const unsigned short* __restrict__ BdT,
    float* __restrict__ outp) {
  const int t0 = blockIdx.y * 128, n0 = blockIdx.x * 128;
  __shared__ unsigned short As[128 * 72];
  __shared__ unsigned short Bs[128 * 72];
  const int tid = threadIdx.x;
  const int w = tid >> 6, ln = tid & 63;
  const int quad = ln >> 4, lane16 = ln & 15;
  const int mbase = (w >> 1) * 64, nbase = (w & 1) * 64;

  f4v acc[4][4] = {};

  for (int k0 = 0; k0 < Gn * Rn; k0 += 64) {
#pragma unroll
    for (int i = 0; i < 8; ++i) {
      int c = tid + i * 256;
      int row = c >> 4, cc = (c & 15) * 4;
      float4 v = *(const float4*)&y[(size_t)(t0 + row) * (Gn * Rn) + k0 + cc];
      ushort4 o;
      o.x = f2bf(v.x); o.y = f2bf(v.y); o.z = f2bf(v.z); o.w = f2bf(v.w);
      *(ushort4*)&As[row * 72 + cc] = o;
    }
#pragma unroll
    for (int i = 0; i < 4; ++i) {
      int c = tid + i * 256;
      int row = c >> 3, cc = (c & 7) * 8;
      *(uint4*)&Bs[row * 72 + cc] = *(const uint4*)&BdT[(size_t)(n0 + row) * (Gn * Rn) + k0 + cc];
    }
    __syncthreads();
#pragma unroll
    for (int kk = 0; kk < 2; ++kk) {
      s8v a[4], b[4];
#pragma unroll
      for (int mt = 0; mt < 4; ++mt)
        a[mt] = *(const s8v*)&As[(mbase + mt * 16 + lane16) * 72 + kk * 32 + quad * 8];
#pragma unroll
      for (int nt = 0; nt < 4; ++nt)
        b[nt] = *(const s8v*)&Bs[(nbase + nt * 16 + lane16) * 72 + kk * 32 + quad * 8];
#pragma unroll
      for (int mt = 0; mt < 4; ++mt)
#pragma unroll
        for (int nt = 0; nt < 4; ++nt)
          acc[mt][nt] = MFMA16(a[mt], b[nt], acc[mt][nt]);
    }
    __syncthreads();
  }
#pragma unroll
  for (int mt = 0; mt < 4; ++mt)
#pragma unroll
    for (int nt = 0; nt < 4; ++nt)
#pragma unroll
      for (int r = 0; r < 4; ++r)
        outp[(size_t)(t0 + mbase + mt * 16 + quad * 4 + r) * Dn +
             n0 + nbase + nt * 16 + lane16] = acc[mt][nt][r];
}

// ---------------------------------------------------------------------------
extern "C" void kernel_launch(void* const* d_in, const int* in_sizes, int n_in,
                              void* d_out, int out_size, void* d_ws, size_t ws_size,
                              hipStream_t stream) {
  const float* hidden = (const float*)d_in[0];
  const float* w_gate = (const float*)d_in[1];
  const float* A_gate = (const float*)d_in[2];
  const float* C_gate = (const float*)d_in[3];
  const float* B_gate = (const float*)d_in[4];
  const float* A_up   = (const float*)d_in[5];
  const float* C_up   = (const float*)d_in[6];
  const float* B_up   = (const float*)d_in[7];
  const float* A_down = (const float*)d_in[8];
  const float* C_down = (const float*)d_in[9];
  const float* B_down = (const float*)d_in[10];
  float* out = (float*)d_out;

  // fp32 region. NOTE: part (fp64 router partials, 16.78 MB) exactly aliases
  // [h1g|h1u|h1d|y] (16.78 MB): part is dead after k_topk, which runs before
  // anything writes h1g/h1u/h1d/y (stream-ordered).
  float* ws     = (float*)d_ws;
  double* part  = (double*)d_ws;               // KSPLIT*2048*256 doubles
  float* h1g    = ws;                          // 1048576
  float* h1u    = h1g + (size_t)T0n * Gn * Rn;
  float* h1d    = h1u + (size_t)T0n * Gn * Rn; // 1048576 (zeroed)
  float* y      = h1d + (size_t)NROWS * Rn;    // 1048576 (zeroed)
  float* rwp    = y + (size_t)T0n * Gn * Rn;   // 16384
  int* sel   = (int*)(rwp + NROWS);            // 16384
  int* rseg  = sel + NROWS;                    // 131072
  int* cnt_e = rseg + Gn * SEGCAP;             // 256
  int* off_e = cnt_e + En;
  int* cur_e = off_e + En;
  int* grp_n = cur_e + En;
  // bf16 region
  unsigned short* Hb   = (unsigned short*)(grp_n + Gn + 8);
  unsigned short* h2gb = Hb + (size_t)T0n * Dn;
  unsigned short* h2ub = h2gb + (size_t)NROWS * Rn;
  unsigned short* AgT  = h2ub + (size_t)NROWS * Rn;      // [G][R][D]
  unsigned short* AuT  = AgT + (size_t)Gn * Rn * Dn;
  unsigned short* BgT  = AuT + (size_t)Gn * Rn * Dn;     // [G][I][R]
  unsigned short* BuT  = BgT + (size_t)Gn * In * Rn;
  unsigned short* AdT  = BuT + (size_t)Gn * In * Rn;     // [G][R][I]
  unsigned short* BdT  = AdT + (size_t)Gn * Rn * In;     // [D][G*R]

  hipMemsetAsync(cnt_e, 0, En * sizeof(int), stream);

  // 1) router partials (fp64 split-K) -> exact expert ordering
  k_router_part<<<dim3(En / 64, T0n / 32, KSPLIT), 256, 0, stream>>>(
      hidden, w_gate, part);
  // 2) top-8 (wave butterfly, fp64 partial reduce) + renorm + expert counts
  k_topk<<<T0n / 4, 256, 0, stream>>>(part, sel, rwp, cnt_e);
  // 3) offsets + scatter rows by expert (expert-major => group-major)
  k_scan<<<1, 64, 0, stream>>>(cnt_e, off_e, cur_e, grp_n);
  k_scatter<<<NROWS / 256, 256, 0, stream>>>(sel, cur_e, rseg);

  // part is now dead; its aliases (h1d, y) can be zeroed.
  hipMemsetAsync(h1d, 0, (size_t)NROWS * Rn * sizeof(float), stream);
  hipMemsetAsync(y,   0, (size_t)T0n * Gn * Rn * sizeof(float), stream);

  // 4) conversions / transposes to bf16 operand layouts (one fused launch + cvt)
  k_cvt<<<(T0n * Dn) / 1024, 256, 0, stream>>>(hidden, Hb, T0n * Dn);
  {
    TD6 D;
    // A_gate [8][2048][64] -> [8][64][2048]
    D.t[0] = {A_gate, AgT, Dn, Rn, Rn / 32, (Rn / 32) * (Dn / 32), 0};
    D.t[1] = {A_up,   AuT, Dn, Rn, Rn / 32, (Rn / 32) * (Dn / 32), 1024};
    // B_gate [8][64][1408] -> [8][1408][64]
    D.t[2] = {B_gate, BgT, Rn, In, In / 32, (In / 32) * (Rn / 32), 2048};
    D.t[3] = {B_up,   BuT, Rn, In, In / 32, (In / 32) * (Rn / 32), 2752};
    // A_down [8][1408][64] -> [8][64][1408]
    D.t[4] = {A_down, AdT, In, Rn, Rn / 32, (Rn / 32) * (In / 32), 3456};
    // B_down [512][2048] -> [2048][512]
    D.t[5] = {B_down, BdT, Gn * Rn, Dn, Dn / 32, (Dn / 32) * (Gn * Rn / 32), 4160};
    k_tcvt6<<<5184, 256, 0, stream>>>(D);
  }

  // 5) dense in-factor projections (MFMA bf16)
  k_h1_mfma<<<dim3(T0n / 128, Gn, 2), 256, 0, stream>>>(Hb, AgT, AuT, h1g, h1u);
  // 6) per-expert core (gate/up), h2 out in bf16
  k_core_gu<<<En, 256, 0, stream>>>(h1g, h1u, C_gate, C_up,
                                    rseg, off_e, cnt_e, h2gb, h2ub);
  // 7) fused expand + down-A (MFMA; inter stays on-chip)
  k_expand_mfma<<<dim3(4, NROWS / 64, Gn), 256, 0, stream>>>(
      h2gb, h2ub, BgT, BuT, AdT, rseg, grp_n, h1d);
  // 8) per-expert down core + rw, reduce to y[t,g,:]
  k_core_down<<<En, 256, 0, stream>>>(h1d, C_down, rwp,
                                      rseg, off_e, cnt_e, y);
  // 9) combine (MFMA bf16)
  k_combine<<<dim3(Dn / 128, T0n / 128), 256, 0, stream>>>(y, BdT, out);
}

// Round 5
// 407.777 us; speedup vs baseline: 2.0522x; 1.1106x over previous
//
#include <hip/hip_runtime.h>
#include <math.h>

// Problem dims
constexpr int T0n = 2048;   // tokens
constexpr int Dn  = 2048;   // hidden
constexpr int En  = 256;    // experts
constexpr int Gn  = 8;      // groups
constexpr int EGn = 32;     // experts per group
constexpr int Rn  = 64;     // tucker rank
constexpr int In  = 1408;   // intermediate

constexpr int NROWS = T0n * 8;    // 16384 dispatched rows
constexpr int SEGCAP = NROWS;     // per-group segment capacity in rseg
constexpr int KSPLIT = 8;         // router split-K factor

typedef __attribute__((ext_vector_type(8))) short s8v;   // 8 bf16
typedef __attribute__((ext_vector_type(4))) float f4v;   // 4 fp32
#define MFMA16(a, b, c) __builtin_amdgcn_mfma_f32_16x16x32_bf16(a, b, c, 0, 0, 0)

__device__ __forceinline__ unsigned short f2bf(float x) {
  unsigned int u = __float_as_uint(x);
  unsigned int r = (u + 0x7FFFu + ((u >> 16) & 1u)) >> 16;
  return (unsigned short)r;
}

// ---------------------------------------------------------------------------
// Fused batched transpose+convert for 9 weight tensors:
// src f32 [batch][rows][cols] -> dst bf16 [batch][cols][rows].
// ---------------------------------------------------------------------------
struct TD { const float* src; unsigned short* dst; int rows, cols, nbx, per_batch, base; };
struct TD9 { TD t[9]; };

__global__ __launch_bounds__(256) void k_tcvt9(TD9 D) {
  __shared__ float tbuf[32][33];
  int id = blockIdx.x;
  int ti = 0;
#pragma unroll
  for (int i = 1; i < 9; ++i) ti = (id >= D.t[i].base) ? i : ti;
  TD d = D.t[ti];
  int local = id - d.base;
  int bz = local / d.per_batch;
  int rem = local - bz * d.per_batch;
  int by = rem / d.nbx;
  int bx = rem - by * d.nbx;

  size_t boff = (size_t)bz * d.rows * d.cols;
  const float* src = d.src + boff;
  unsigned short* dst = d.dst + boff;
  int c0 = bx * 32, r0 = by * 32;
  int tx = threadIdx.x & 31, ty = threadIdx.x >> 5;   // ty 0..7
  for (int i = ty; i < 32; i += 8)
    tbuf[i][tx] = src[(size_t)(r0 + i) * d.cols + c0 + tx];
  __syncthreads();
  for (int i = ty; i < 32; i += 8)
    dst[(size_t)(c0 + i) * d.rows + r0 + tx] = f2bf(tbuf[tx][i]);
}

// ---------------------------------------------------------------------------
// Router logits, split-K, FP64 accumulation (exact expert ordering).
// LDS tiles held in FP64 so the inner loop is pure v_fma_f64 (no per-kk cvt).
// grid (E/64, T0/32, KSPLIT=8).
// ---------------------------------------------------------------------------
__global__ __launch_bounds__(256) void k_router_part(
    const float* __restrict__ A, const float* __restrict__ B,
    double* __restrict__ part) {
  __shared__ double As[32][33];
  __shared__ double Bs[32][64];
  const int m0 = blockIdx.y * 32, n0 = blockIdx.x * 64;
  const int kc = blockIdx.z;
  const int kbeg = kc * (Dn / KSPLIT), kend = kbeg + Dn / KSPLIT;
  const int tid = threadIdx.x;
  const int ty = tid >> 4, tx = tid & 15;
  const int lm = tid >> 3;
  const int lk4 = (tid & 7) << 2;

  double acc[2][4] = {{0, 0, 0, 0}, {0, 0, 0, 0}};

  for (int k0 = kbeg; k0 < kend; k0 += 32) {
    float4 av = *(const float4*)&A[(size_t)(m0 + lm) * Dn + k0 + lk4];
    As[lk4 + 0][lm] = (double)av.x; As[lk4 + 1][lm] = (double)av.y;
    As[lk4 + 2][lm] = (double)av.z; As[lk4 + 3][lm] = (double)av.w;
#pragma unroll
    for (int q = 0; q < 2; ++q) {
      int idx = tid * 2 + q;
      int br = idx >> 4, bc = (idx & 15) << 2;
      float4 bv = *(const float4*)&B[(size_t)(k0 + br) * En + n0 + bc];
      Bs[br][bc + 0] = (double)bv.x; Bs[br][bc + 1] = (double)bv.y;
      Bs[br][bc + 2] = (double)bv.z; Bs[br][bc + 3] = (double)bv.w;
    }
    __syncthreads();
#pragma unroll
    for (int kk = 0; kk < 32; ++kk) {
      double a0 = As[kk][ty * 2 + 0];
      double a1 = As[kk][ty * 2 + 1];
      double b0 = Bs[kk][tx * 4 + 0], b1 = Bs[kk][tx * 4 + 1];
      double b2 = Bs[kk][tx * 4 + 2], b3 = Bs[kk][tx * 4 + 3];
      acc[0][0] += a0 * b0; acc[0][1] += a0 * b1;
      acc[0][2] += a0 * b2; acc[0][3] += a0 * b3;
      acc[1][0] += a1 * b0; acc[1][1] += a1 * b1;
      acc[1][2] += a1 * b2; acc[1][3] += a1 * b3;
    }
    __syncthreads();
  }
  double* prow = part + (size_t)kc * T0n * En;
#pragma unroll
  for (int i = 0; i < 2; ++i)
#pragma unroll
    for (int jj = 0; jj < 4; ++jj)
      prow[(size_t)(m0 + ty * 2 + i) * En + tx * 4 + n0 + jj] = acc[i][jj];
}

// ---------------------------------------------------------------------------
// Top-8: one wave per token, shuffle butterfly. Sums KSPLIT fp64 partials.
// ---------------------------------------------------------------------------
__global__ __launch_bounds__(256) void k_topk(
    const double* __restrict__ part, int* __restrict__ sel,
    float* __restrict__ rw, int* __restrict__ cnt_e) {
  const int wid = threadIdx.x >> 6, ln = threadIdx.x & 63;
  const int t = blockIdx.x * 4 + wid;

  double v[4];
#pragma unroll
  for (int j = 0; j < 4; ++j) {
    double s = 0.0;
#pragma unroll
    for (int kc = 0; kc < KSPLIT; ++kc)
      s += part[((size_t)kc * T0n + t) * En + ln + 64 * j];
    v[j] = s;
  }

  float topv[8];
  int topi[8];
#pragma unroll
  for (int k = 0; k < 8; ++k) {
    double bv = v[0]; int bi = ln;
#pragma unroll
    for (int j = 1; j < 4; ++j) {
      int cand = ln + 64 * j;
      if (v[j] > bv || (v[j] == bv && cand < bi)) { bv = v[j]; bi = cand; }
    }
#pragma unroll
    for (int off = 32; off > 0; off >>= 1) {
      double ov = __shfl_xor(bv, off);
      int oi = __shfl_xor(bi, off);
      if (ov > bv || (ov == bv && oi < bi)) { bv = ov; bi = oi; }
    }
    topv[k] = (float)bv; topi[k] = bi;
    if ((bi & 63) == ln) v[bi >> 6] = -1e300;
  }

  if (ln < 8) {
    float m = topv[0];
    float ssum = 0.f;
#pragma unroll
    for (int k = 0; k < 8; ++k) ssum += expf(topv[k] - m);
    rw[t * 8 + ln] = expf(topv[ln] - m) / ssum;
    sel[t * 8 + ln] = topi[ln];
    atomicAdd(&cnt_e[topi[ln]], 1);
  }
}

__global__ void k_scan(const int* __restrict__ cnt_e, int* __restrict__ off_e,
                       int* __restrict__ cur_e, int* __restrict__ grp_n) {
  if (threadIdx.x == 0 && blockIdx.x == 0) {
    for (int g = 0; g < Gn; ++g) {
      int run = 0;
      for (int ei = 0; ei < EGn; ++ei) {
        int e = g * EGn + ei;
        off_e[e] = g * SEGCAP + run;
        cur_e[e] = g * SEGCAP + run;
        run += cnt_e[e];
      }
      grp_n[g] = run;
    }
  }
}

__global__ void k_scatter(const int* __restrict__ sel, int* __restrict__ cur_e,
                          int* __restrict__ rseg) {
  int i = blockIdx.x * 256 + threadIdx.x;
  int e = sel[i];
  int pos = atomicAdd(&cur_e[e], 1);
  rseg[pos] = i;
}

// ---------------------------------------------------------------------------
// h1 = H @ A_fac[g], gate+up in one block (A-fragment reuse), H f32 staged
// with on-the-fly bf16 convert. grid (T0/64, G).
// ---------------------------------------------------------------------------
__global__ __launch_bounds__(256) void k_h1_mfma(
    const float* __restrict__ H,
    const unsigned short* __restrict__ AgT, const unsigned short* __restrict__ AuT,
    float* __restrict__ h1g, float* __restrict__ h1u) {
  const int t0 = blockIdx.x * 64;
  const int g = blockIdx.y;
  const unsigned short* Wg = AgT + (size_t)g * Rn * Dn;
  const unsigned short* Wu = AuT + (size_t)g * Rn * Dn;

  __shared__ unsigned short As[64 * 72];
  __shared__ unsigned short Bg_l[64 * 72];
  __shared__ unsigned short Bu_l[64 * 72];
  const int tid = threadIdx.x;
  const int w = tid >> 6, ln = tid & 63;
  const int quad = ln >> 4, lane16 = ln & 15;
  const int j = tid >> 2, q = (tid & 3) * 16;

  f4v Sg[4] = {}, Su[4] = {};

  for (int k0 = 0; k0 < Dn; k0 += 64) {
#pragma unroll
    for (int i = 0; i < 4; ++i) {
      float4 v = *(const float4*)&H[(size_t)(t0 + j) * Dn + k0 + q + i * 4];
      ushort4 o;
      o.x = f2bf(v.x); o.y = f2bf(v.y); o.z = f2bf(v.z); o.w = f2bf(v.w);
      *(ushort4*)&As[j * 72 + q + i * 4] = o;
    }
    *(uint4*)&Bg_l[j * 72 + q + 0] = *(const uint4*)&Wg[(size_t)j * Dn + k0 + q + 0];
    *(uint4*)&Bg_l[j * 72 + q + 8] = *(const uint4*)&Wg[(size_t)j * Dn + k0 + q + 8];
    *(uint4*)&Bu_l[j * 72 + q + 0] = *(const uint4*)&Wu[(size_t)j * Dn + k0 + q + 0];
    *(uint4*)&Bu_l[j * 72 + q + 8] = *(const uint4*)&Wu[(size_t)j * Dn + k0 + q + 8];
    __syncthreads();
#pragma unroll
    for (int kk = 0; kk < 2; ++kk) {
      s8v a = *(const s8v*)&As[(w * 16 + lane16) * 72 + kk * 32 + quad * 8];
#pragma unroll
      for (int nt = 0; nt < 4; ++nt) {
        s8v bg = *(const s8v*)&Bg_l[(nt * 16 + lane16) * 72 + kk * 32 + quad * 8];
        s8v bu = *(const s8v*)&Bu_l[(nt * 16 + lane16) * 72 + kk * 32 + quad * 8];
        Sg[nt] = MFMA16(a, bg, Sg[nt]);
        Su[nt] = MFMA16(a, bu, Su[nt]);
      }
    }
    __syncthreads();
  }
#pragma unroll
  for (int nt = 0; nt < 4; ++nt)
#pragma unroll
    for (int r = 0; r < 4; ++r) {
      int row = t0 + w * 16 + quad * 4 + r;
      int col = g * 64 + nt * 16 + lane16;
      h1g[(size_t)row * (Gn * Rn) + col] = Sg[nt][r];
      h1u[(size_t)row * (Gn * Rn) + col] = Su[nt][r];
    }
}

// ---------------------------------------------------------------------------
// Per-expert core (gate/up) via MFMA: h2 = h1 @ C_e, C^T bf16 staged in LDS.
// One block per expert; 64-row tiles of gathered rows.
// ---------------------------------------------------------------------------
__global__ __launch_bounds__(256) void k_core_gu(
    const float* __restrict__ h1g, const float* __restrict__ h1u,
    const unsigned short* __restrict__ CgT, const unsigned short* __restrict__ CuT,
    const int* __restrict__ rseg, const int* __restrict__ off_e,
    const int* __restrict__ cnt_e,
    unsigned short* __restrict__ h2gb, unsigned short* __restrict__ h2ub) {
  const int e = blockIdx.x;
  const int ne = cnt_e[e];
  if (ne == 0) return;
  const int g = e >> 5;
  const int base = off_e[e];
  __shared__ unsigned short Bg_l[64 * 72];
  __shared__ unsigned short Bu_l[64 * 72];
  __shared__ unsigned short Ag_l[64 * 72];
  __shared__ unsigned short Au_l[64 * 72];
  __shared__ int rids[64];
  const int tid = threadIdx.x;
  const int w = tid >> 6, ln = tid & 63;
  const int quad = ln >> 4, lane16 = ln & 15;
  const int j = tid >> 2, q = (tid & 3) * 16;
  {
    const unsigned short* cg = CgT + (size_t)e * (Rn * Rn);
    const unsigned short* cu = CuT + (size_t)e * (Rn * Rn);
    *(uint4*)&Bg_l[j * 72 + q + 0] = *(const uint4*)&cg[j * 64 + q + 0];
    *(uint4*)&Bg_l[j * 72 + q + 8] = *(const uint4*)&cg[j * 64 + q + 8];
    *(uint4*)&Bu_l[j * 72 + q + 0] = *(const uint4*)&cu[j * 64 + q + 0];
    *(uint4*)&Bu_l[j * 72 + q + 8] = *(const uint4*)&cu[j * 64 + q + 8];
  }
  const int ntile = (ne + 63) >> 6;
  for (int it = 0; it < ntile; ++it) {
    int mi = it * 64 + j;
    int rid = (mi < ne) ? rseg[base + mi] : -1;
    if ((tid & 3) == 0) rids[j] = rid;
#pragma unroll
    for (int i = 0; i < 4; ++i) {
      int kb = q + i * 4;
      float4 vg = {0.f, 0.f, 0.f, 0.f}, vu = {0.f, 0.f, 0.f, 0.f};
      if (rid >= 0) {
        vg = *(const float4*)&h1g[(size_t)(rid >> 3) * (Gn * Rn) + g * 64 + kb];
        vu = *(const float4*)&h1u[(size_t)(rid >> 3) * (Gn * Rn) + g * 64 + kb];
      }
      ushort4 og, ou;
      og.x = f2bf(vg.x); og.y = f2bf(vg.y); og.z = f2bf(vg.z); og.w = f2bf(vg.w);
      ou.x = f2bf(vu.x); ou.y = f2bf(vu.y); ou.z = f2bf(vu.z); ou.w = f2bf(vu.w);
      *(ushort4*)&Ag_l[j * 72 + kb] = og;
      *(ushort4*)&Au_l[j * 72 + kb] = ou;
    }
    __syncthreads();
    f4v Sg[4] = {}, Su[4] = {};
#pragma unroll
    for (int kk = 0; kk < 2; ++kk) {
      s8v ag = *(const s8v*)&Ag_l[(w * 16 + lane16) * 72 + kk * 32 + quad * 8];
      s8v au = *(const s8v*)&Au_l[(w * 16 + lane16) * 72 + kk * 32 + quad * 8];
#pragma unroll
      for (int nt = 0; nt < 4; ++nt) {
        s8v bg = *(const s8v*)&Bg_l[(nt * 16 + lane16) * 72 + kk * 32 + quad * 8];
        s8v bu = *(const s8v*)&Bu_l[(nt * 16 + lane16) * 72 + kk * 32 + quad * 8];
        Sg[nt] = MFMA16(ag, bg, Sg[nt]);
        Su[nt] = MFMA16(au, bu, Su[nt]);
      }
    }
#pragma unroll
    for (int nt = 0; nt < 4; ++nt)
#pragma unroll
      for (int r = 0; r < 4; ++r) {
        int lrow = w * 16 + quad * 4 + r;
        int rid2 = rids[lrow];
        if (rid2 >= 0) {
          h2gb[(size_t)rid2 * 64 + nt * 16 + lane16] = f2bf(Sg[nt][r]);
          h2ub[(size_t)rid2 * 64 + nt * 16 + lane16] = f2bf(Su[nt][r]);
        }
      }
    __syncthreads();
  }
}

// ---------------------------------------------------------------------------
// Fused expand + down-A via MFMA (inter stays on-chip).
// grid (4 I-splits, NROWS/64 row tiles, G).
// ---------------------------------------------------------------------------
__global__ __launch_bounds__(256) void k_expand_mfma(
    const unsigned short* __restrict__ h2gb, const unsigned short* __restrict__ h2ub,
    const unsigned short* __restrict__ BgT, const unsigned short* __restrict__ BuT,
    const unsigned short* __restrict__ AdT,
    const int* __restrict__ rseg, const int* __restrict__ grp_n,
    float* __restrict__ h1d) {
  const int g = blockIdx.z;
  const int ng = grp_n[g];
  const int m0 = blockIdx.y * 64;
  if (m0 >= ng) return;
  const int c_beg = blockIdx.x * 6;
  const int c_end = min(22, c_beg + 6);

  __shared__ unsigned short Hg_l[64 * 72];
  __shared__ unsigned short Hu_l[64 * 72];
  __shared__ unsigned short Bg_l[64 * 72];
  __shared__ unsigned short Bu_l[64 * 72];
  __shared__ unsigned short Ad_l[64 * 72];
  __shared__ int rids[64];

  const int tid = threadIdx.x;
  const int w = tid >> 6, ln = tid & 63;
  const int quad = ln >> 4, lane16 = ln & 15;

  if (tid < 64) rids[tid] = (m0 + tid < ng) ? rseg[g * SEGCAP + m0 + tid] : -1;
  __syncthreads();
#pragma unroll
  for (int i = 0; i < 2; ++i) {
    int c = tid + i * 256;
    int row = c >> 3, cc = (c & 7) * 8;
    int rid = rids[row];
    uint4 zg = {0, 0, 0, 0}, zu = {0, 0, 0, 0};
    if (rid >= 0) {
      zg = *(const uint4*)&h2gb[(size_t)rid * 64 + cc];
      zu = *(const uint4*)&h2ub[(size_t)rid * 64 + cc];
    }
    *(uint4*)&Hg_l[row * 72 + cc] = zg;
    *(uint4*)&Hu_l[row * 72 + cc] = zu;
  }

  const unsigned short* Bg_base = BgT + (size_t)g * In * Rn;
  const unsigned short* Bu_base = BuT + (size_t)g * In * Rn;
  const unsigned short* Ad_base = AdT + (size_t)g * Rn * In;

  f4v P[4] = {};

  for (int c = c_beg; c < c_end; ++c) {
    const int i0 = c * 64;
#pragma unroll
    for (int i = 0; i < 2; ++i) {
      int cq = tid + i * 256;
      int row = cq >> 3, co = (cq & 7) * 8;
      *(uint4*)&Bg_l[row * 72 + co] = *(const uint4*)&Bg_base[(size_t)(i0 + row) * Rn + co];
      *(uint4*)&Bu_l[row * 72 + co] = *(const uint4*)&Bu_base[(size_t)(i0 + row) * Rn + co];
      *(uint4*)&Ad_l[row * 72 + co] = *(const uint4*)&Ad_base[(size_t)row * In + i0 + co];
    }
    __syncthreads();

    f4v Sg[4] = {}, Su[4] = {};
#pragma unroll
    for (int kk = 0; kk < 2; ++kk) {
      s8v ag = *(const s8v*)&Hg_l[(w * 16 + lane16) * 72 + kk * 32 + quad * 8];
      s8v au = *(const s8v*)&Hu_l[(w * 16 + lane16) * 72 + kk * 32 + quad * 8];
#pragma unroll
      for (int nt = 0; nt < 4; ++nt) {
        s8v bg = *(const s8v*)&Bg_l[(nt * 16 + lane16) * 72 + kk * 32 + quad * 8];
        s8v bu = *(const s8v*)&Bu_l[(nt * 16 + lane16) * 72 + kk * 32 + quad * 8];
        Sg[nt] = MFMA16(ag, bg, Sg[nt]);
        Su[nt] = MFMA16(au, bu, Su[nt]);
      }
    }
    __syncthreads();
#pragma unroll
    for (int nt = 0; nt < 4; ++nt)
#pragma unroll
      for (int r = 0; r < 4; ++r) {
        float sg = Sg[nt][r];
        float v = sg / (1.f + __expf(-sg)) * Su[nt][r];
        Bg_l[(w * 16 + quad * 4 + r) * 72 + nt * 16 + lane16] = f2bf(v);
      }
    __syncthreads();
#pragma unroll
    for (int kk = 0; kk < 2; ++kk) {
      s8v ai = *(const s8v*)&Bg_l[(w * 16 + lane16) * 72 + kk * 32 + quad * 8];
#pragma unroll
      for (int nt = 0; nt < 4; ++nt) {
        s8v bd = *(const s8v*)&Ad_l[(nt * 16 + lane16) * 72 + kk * 32 + quad * 8];
        P[nt] = MFMA16(ai, bd, P[nt]);
      }
    }
    __syncthreads();
  }

#pragma unroll
  for (int nt = 0; nt < 4; ++nt)
#pragma unroll
    for (int r = 0; r < 4; ++r) {
      int lrow = w * 16 + quad * 4 + r;
      int rid = rids[lrow];
      if (rid >= 0)
        atomicAdd(&h1d[(size_t)rid * 64 + nt * 16 + lane16], P[nt][r]);
    }
}

// ---------------------------------------------------------------------------
// Per-expert down core via MFMA + routing weight, reduce to y[t,g,64].
// ---------------------------------------------------------------------------
__global__ __launch_bounds__(256) void k_core_down(
    const float* __restrict__ h1d, const unsigned short* __restrict__ CdT,
    const float* __restrict__ rw,
    const int* __restrict__ rseg, const int* __restrict__ off_e,
    const int* __restrict__ cnt_e,
    float* __restrict__ y) {
  const int e = blockIdx.x;
  const int ne = cnt_e[e];
  if (ne == 0) return;
  const int g = e >> 5;
  const int base = off_e[e];
  __shared__ unsigned short Bd_l[64 * 72];
  __shared__ unsigned short Ad_l[64 * 72];
  __shared__ int rids[64];
  const int tid = threadIdx.x;
  const int w = tid >> 6, ln = tid & 63;
  const int quad = ln >> 4, lane16 = ln & 15;
  const int j = tid >> 2, q = (tid & 3) * 16;
  {
    const unsigned short* cd = CdT + (size_t)e * (Rn * Rn);
    *(uint4*)&Bd_l[j * 72 + q + 0] = *(const uint4*)&cd[j * 64 + q + 0];
    *(uint4*)&Bd_l[j * 72 + q + 8] = *(const uint4*)&cd[j * 64 + q + 8];
  }
  const int ntile = (ne + 63) >> 6;
  for (int it = 0; it < ntile; ++it) {
    int mi = it * 64 + j;
    int rid = (mi < ne) ? rseg[base + mi] : -1;
    if ((tid & 3) == 0) rids[j] = rid;
#pragma unroll
    for (int i = 0; i < 4; ++i) {
      int kb = q + i * 4;
      float4 vd = {0.f, 0.f, 0.f, 0.f};
      if (rid >= 0) vd = *(const float4*)&h1d[(size_t)rid * 64 + kb];
      ushort4 od;
      od.x = f2bf(vd.x); od.y = f2bf(vd.y); od.z = f2bf(vd.z); od.w = f2bf(vd.w);
      *(ushort4*)&Ad_l[j * 72 + kb] = od;
    }
    __syncthreads();
    f4v Sd[4] = {};
#pragma unroll
    for (int kk = 0; kk < 2; ++kk) {
      s8v ad = *(const s8v*)&Ad_l[(w * 16 + lane16) * 72 + kk * 32 + quad * 8];
#pragma unroll
      for (int nt = 0; nt < 4; ++nt) {
        s8v bd = *(const s8v*)&Bd_l[(nt * 16 + lane16) * 72 + kk * 32 + quad * 8];
        Sd[nt] = MFMA16(ad, bd, Sd[nt]);
      }
    }
#pragma unroll
    for (int nt = 0; nt < 4; ++nt)
#pragma unroll
      for (int r = 0; r < 4; ++r) {
        int lrow = w * 16 + quad * 4 + r;
        int rid2 = rids[lrow];
        if (rid2 >= 0) {
          float wgt = rw[rid2];
          atomicAdd(&y[(size_t)(rid2 >> 3) * (Gn * Rn) + g * 64 + nt * 16 + lane16],
                    wgt * Sd[nt][r]);
        }
      }
    __syncthreads();
  }
}

// ---------------------------------------------------------------------------
// Combine: out[2048,2048] = y[2048,512] @ B_down-as-[512,2048], MFMA bf16.
// ---------------------------------------------------------------------------
__global__ __launch_bounds__(256) void k_combine(
    const float* __restrict__ y, const unsigned short* __restrict__ BdT,
    float* __restrict__ outp) {
  const int t0 = blockIdx.y * 128, n0 = blockIdx.x * 128;
  __shared__ unsigned short As[128 * 72];
  __shared__ unsigned short Bs[128 * 72];
  const int tid = threadIdx.x;
  const int w = tid >> 6, ln = tid & 63;
  const int quad = ln >> 4, lane16 = ln & 15;
  const int mbase = (w >> 1) * 64, nbase = (w & 1) * 64;

  f4v acc[4][4] = {};

  for (int k0 = 0; k0 < Gn * Rn; k0 += 64) {
#pragma unroll
    for (int i = 0; i < 8; ++i) {
      int c = tid + i * 256;
      int row = c >> 4, cc = (c & 15) * 4;
      float4 v = *(const float4*)&y[(size_t)(t0 + row) * (Gn * Rn) + k0 + cc];
      ushort4 o;
      o.x = f2bf(v.x); o.y = f2bf(v.y); o.z = f2bf(v.z); o.w = f2bf(v.w);
      *(ushort4*)&As[row * 72 + cc] = o;
    }
#pragma unroll
    for (int i = 0; i < 4; ++i) {
      int c = tid + i * 256;
      int row = c >> 3, cc = (c & 7) * 8;
      *(uint4*)&Bs[row * 72 + cc] = *(const uint4*)&BdT[(size_t)(n0 + row) * (Gn * Rn) + k0 + cc];
    }
    __syncthreads();
#pragma unroll
    for (int kk = 0; kk < 2; ++kk) {
      s8v a[4], b[4];
#pragma unroll
      for (int mt = 0; mt < 4; ++mt)
        a[mt] = *(const s8v*)&As[(mbase + mt * 16 + lane16) * 72 + kk * 32 + quad * 8];
#pragma unroll
      for (int nt = 0; nt < 4; ++nt)
        b[nt] = *(const s8v*)&Bs[(nbase + nt * 16 + lane16) * 72 + kk * 32 + quad * 8];
#pragma unroll
      for (int mt = 0; mt < 4; ++mt)
#pragma unroll
        for (int nt = 0; nt < 4; ++nt)
          acc[mt][nt] = MFMA16(a[mt], b[nt], acc[mt][nt]);
    }
    __syncthreads();
  }
#pragma unroll
  for (int mt = 0; mt < 4; ++mt)
#pragma unroll
    for (int nt = 0; nt < 4; ++nt)
#pragma unroll
      for (int r = 0; r < 4; ++r)
        outp[(size_t)(t0 + mbase + mt * 16 + quad * 4 + r) * Dn +
             n0 + nbase + nt * 16 + lane16] = acc[mt][nt][r];
}

// ---------------------------------------------------------------------------
extern "C" void kernel_launch(void* const* d_in, const int* in_sizes, int n_in,
                              void* d_out, int out_size, void* d_ws, size_t ws_size,
                              hipStream_t stream) {
  const float* hidden = (const float*)d_in[0];
  const float* w_gate = (const float*)d_in[1];
  const float* A_gate = (const float*)d_in[2];
  const float* C_gate = (const float*)d_in[3];
  const float* B_gate = (const float*)d_in[4];
  const float* A_up   = (const float*)d_in[5];
  const float* C_up   = (const float*)d_in[6];
  const float* B_up   = (const float*)d_in[7];
  const float* A_down = (const float*)d_in[8];
  const float* C_down = (const float*)d_in[9];
  const float* B_down = (const float*)d_in[10];
  float* out = (float*)d_out;

  // Workspace layout (bytes). part = fp64 router partials, KSPLIT*T0*E*8 =
  // 33,554,432 B at offset 0. EVERYTHING in [0, 33.55MB) is written only
  // AFTER k_topk consumes part (stream-ordered), so aliasing is safe.
  char* base = (char*)d_ws;
  double* part = (double*)d_ws;
  size_t o = 0;
  unsigned short* h2gb = (unsigned short*)(base + o); o += (size_t)NROWS * Rn * 2;        // 2.10MB
  unsigned short* h2ub = (unsigned short*)(base + o); o += (size_t)NROWS * Rn * 2;        // 2.10MB
  unsigned short* AgT  = (unsigned short*)(base + o); o += (size_t)Gn * Rn * Dn * 2;      // 2.10MB
  unsigned short* AuT  = (unsigned short*)(base + o); o += (size_t)Gn * Rn * Dn * 2;      // 2.10MB
  unsigned short* BgT  = (unsigned short*)(base + o); o += (size_t)Gn * In * Rn * 2;      // 1.44MB
  unsigned short* BuT  = (unsigned short*)(base + o); o += (size_t)Gn * In * Rn * 2;      // 1.44MB
  unsigned short* AdT  = (unsigned short*)(base + o); o += (size_t)Gn * Rn * In * 2;      // 1.44MB
  unsigned short* BdT  = (unsigned short*)(base + o); o += (size_t)Dn * Gn * Rn * 2;      // 2.10MB
  unsigned short* CgT  = (unsigned short*)(base + o); o += (size_t)En * Rn * Rn * 2;      // 2.10MB
  unsigned short* CuT  = (unsigned short*)(base + o); o += (size_t)En * Rn * Rn * 2;      // 2.10MB
  unsigned short* CdT  = (unsigned short*)(base + o); o += (size_t)En * Rn * Rn * 2;      // 2.10MB
  float* h1g = (float*)(base + o); o += (size_t)T0n * Gn * Rn * 4;                        // 4.19MB
  float* h1u = (float*)(base + o); o += (size_t)T0n * Gn * Rn * 4;                        // 4.19MB
  float* h1d = (float*)(base + o); o += (size_t)NROWS * Rn * 4;   // ends 33.69MB >= part end
  float* y   = (float*)(base + o); o += (size_t)T0n * Gn * Rn * 4;
  float* rwp = (float*)(base + o); o += (size_t)NROWS * 4;
  int* sel   = (int*)(base + o); o += (size_t)NROWS * 4;
  int* rseg  = (int*)(base + o); o += (size_t)Gn * SEGCAP * 4;
  int* cnt_e = (int*)(base + o); o += En * 4;
  int* off_e = (int*)(base + o); o += En * 4;
  int* cur_e = (int*)(base + o); o += En * 4;
  int* grp_n = (int*)(base + o); o += Gn * 4;

  hipMemsetAsync(cnt_e, 0, En * sizeof(int), stream);

  // 1) router partials (fp64 split-K, fp64 LDS) -> exact expert ordering
  k_router_part<<<dim3(En / 64, T0n / 32, KSPLIT), 256, 0, stream>>>(
      hidden, w_gate, part);
  // 2) top-8 + renorm + expert counts
  k_topk<<<T0n / 4, 256, 0, stream>>>(part, sel, rwp, cnt_e);
  // 3) offsets + scatter rows by expert (expert-major => group-major)
  k_scan<<<1, 64, 0, stream>>>(cnt_e, off_e, cur_e, grp_n);
  k_scatter<<<NROWS / 256, 256, 0, stream>>>(sel, cur_e, rseg);

  // part is now dead; aliased buffers may be written.
  hipMemsetAsync(h1d, 0, (size_t)NROWS * Rn * sizeof(float), stream);
  hipMemsetAsync(y,   0, (size_t)T0n * Gn * Rn * sizeof(float), stream);

  // 4) transpose+convert all 9 weight tensors to bf16 operand layouts
  {
    TD9 D;
    D.t[0] = {A_gate, AgT, Dn, Rn, Rn / 32, (Rn / 32) * (Dn / 32), 0};          // 1024
    D.t[1] = {A_up,   AuT, Dn, Rn, Rn / 32, (Rn / 32) * (Dn / 32), 1024};       // 1024
    D.t[2] = {B_gate, BgT, Rn, In, In / 32, (In / 32) * (Rn / 32), 2048};       // 704
    D.t[3] = {B_up,   BuT, Rn, In, In / 32, (In / 32) * (Rn / 32), 2752};       // 704
    D.t[4] = {A_down, AdT, In, Rn, Rn / 32, (Rn / 32) * (In / 32), 3456};       // 704
    D.t[5] = {B_down, BdT, Gn * Rn, Dn, Dn / 32, (Dn / 32) * (Gn * Rn / 32), 4160}; // 1024
    D.t[6] = {C_gate, CgT, Rn, Rn, 2, 4, 5184};                                 // 1024
    D.t[7] = {C_up,   CuT, Rn, Rn, 2, 4, 6208};                                 // 1024
    D.t[8] = {C_down, CdT, Rn, Rn, 2, 4, 7232};                                 // 1024
    k_tcvt9<<<8256, 256, 0, stream>>>(D);
  }

  // 5) dense in-factor projections, gate+up fused (MFMA bf16, H f32 staged)
  k_h1_mfma<<<dim3(T0n / 64, Gn), 256, 0, stream>>>(hidden, AgT, AuT, h1g, h1u);
  // 6) per-expert core (gate/up) via MFMA, h2 out in bf16
  k_core_gu<<<En, 256, 0, stream>>>(h1g, h1u, CgT, CuT,
                                    rseg, off_e, cnt_e, h2gb, h2ub);
  // 7) fused expand + down-A (MFMA; inter stays on-chip)
  k_expand_mfma<<<dim3(4, NROWS / 64, Gn), 256, 0, stream>>>(
      h2gb, h2ub, BgT, BuT, AdT, rseg, grp_n, h1d);
  // 8) per-expert down core via MFMA + rw, reduce to y[t,g,:]
  k_core_down<<<En, 256, 0, stream>>>(h1d, CdT, rwp,
                                      rseg, off_e, cnt_e, y);
  // 9) combine (MFMA bf16)
  k_combine<<<dim3(Dn / 128, T0n / 128), 256, 0, stream>>>(y, BdT, out);
}

// Round 6
// 375.445 us; speedup vs baseline: 2.2289x; 1.0861x over previous
//
#include <hip/hip_runtime.h>
#include <math.h>

// Problem dims
constexpr int T0n = 2048;   // tokens
constexpr int Dn  = 2048;   // hidden
constexpr int En  = 256;    // experts
constexpr int Gn  = 8;      // groups
constexpr int EGn = 32;     // experts per group
constexpr int Rn  = 64;     // tucker rank
constexpr int In  = 1408;   // intermediate

constexpr int NROWS = T0n * 8;    // 16384 dispatched rows
constexpr int SEGCAP = NROWS;     // per-group segment capacity in rseg
constexpr int KSPLIT = 8;         // router split-K factor

typedef __attribute__((ext_vector_type(8))) short s8v;   // 8 bf16
typedef __attribute__((ext_vector_type(4))) float f4v;   // 4 fp32
#define MFMA16(a, b, c) __builtin_amdgcn_mfma_f32_16x16x32_bf16(a, b, c, 0, 0, 0)

__device__ __forceinline__ unsigned short f2bf(float x) {
  unsigned int u = __float_as_uint(x);
  unsigned int r = (u + 0x7FFFu + ((u >> 16) & 1u)) >> 16;
  return (unsigned short)r;
}

// ---------------------------------------------------------------------------
// Fused batched transpose+convert for 9 weight tensors:
// src f32 [batch][rows][cols] -> dst bf16 [batch][cols][rows].
// ---------------------------------------------------------------------------
struct TD { const float* src; unsigned short* dst; int rows, cols, nbx, per_batch, base; };
struct TD9 { TD t[9]; };

__global__ __launch_bounds__(256) void k_tcvt9(TD9 D) {
  __shared__ float tbuf[32][33];
  int id = blockIdx.x;
  int ti = 0;
#pragma unroll
  for (int i = 1; i < 9; ++i) ti = (id >= D.t[i].base) ? i : ti;
  TD d = D.t[ti];
  int local = id - d.base;
  int bz = local / d.per_batch;
  int rem = local - bz * d.per_batch;
  int by = rem / d.nbx;
  int bx = rem - by * d.nbx;

  size_t boff = (size_t)bz * d.rows * d.cols;
  const float* src = d.src + boff;
  unsigned short* dst = d.dst + boff;
  int c0 = bx * 32, r0 = by * 32;
  int tx = threadIdx.x & 31, ty = threadIdx.x >> 5;   // ty 0..7
  for (int i = ty; i < 32; i += 8)
    tbuf[i][tx] = src[(size_t)(r0 + i) * d.cols + c0 + tx];
  __syncthreads();
  for (int i = ty; i < 32; i += 8)
    dst[(size_t)(c0 + i) * d.rows + r0 + tx] = f2bf(tbuf[tx][i]);
}

// ---------------------------------------------------------------------------
// Router logits, split-K, FP64 register accumulation (exact expert ordering).
// LDS tiles in FP32 (4-byte banks: the fp64-LDS version had 8-way conflicts,
// SQ_LDS_BANK_CONFLICT 2.4e7 — R5 post-mortem). 64x64 block tile, 4x4/thread:
// per kk: 2 ds_read_b128 + 8 cvt_f64_f32 + 16 v_fma_f64.
// grid (E/64, T0/64, KSPLIT=8).
// ---------------------------------------------------------------------------
__global__ __launch_bounds__(256) void k_router_part(
    const float* __restrict__ A, const float* __restrict__ B,
    double* __restrict__ part) {
  __shared__ float As[32][68];   // [k][m] transposed; 68: 16B-aligned rows, <=2-way banks
  __shared__ float Bs[32][68];   // [k][n]
  const int m0 = blockIdx.y * 64, n0 = blockIdx.x * 64;
  const int kc = blockIdx.z;
  const int kbeg = kc * (Dn / KSPLIT);   // 256-wide K slice
  const int tid = threadIdx.x;
  const int ty = tid >> 4, tx = tid & 15;
  const int lm = tid & 63, lk8 = (tid >> 6) * 8;   // A loader: row lm, k cols lk8..+7
  const int br = tid >> 3, bc = (tid & 7) * 8;     // B loader: k row br, n cols bc..+7

  double acc[4][4] = {};

  for (int k0 = kbeg; k0 < kbeg + Dn / KSPLIT; k0 += 32) {
    float4 a0 = *(const float4*)&A[(size_t)(m0 + lm) * Dn + k0 + lk8];
    float4 a1 = *(const float4*)&A[(size_t)(m0 + lm) * Dn + k0 + lk8 + 4];
    As[lk8 + 0][lm] = a0.x; As[lk8 + 1][lm] = a0.y;
    As[lk8 + 2][lm] = a0.z; As[lk8 + 3][lm] = a0.w;
    As[lk8 + 4][lm] = a1.x; As[lk8 + 5][lm] = a1.y;
    As[lk8 + 6][lm] = a1.z; As[lk8 + 7][lm] = a1.w;
    *(float4*)&Bs[br][bc]     = *(const float4*)&B[(size_t)(k0 + br) * En + n0 + bc];
    *(float4*)&Bs[br][bc + 4] = *(const float4*)&B[(size_t)(k0 + br) * En + n0 + bc + 4];
    __syncthreads();
#pragma unroll
    for (int kk = 0; kk < 32; ++kk) {
      float4 af = *(const float4*)&As[kk][ty * 4];
      float4 bf = *(const float4*)&Bs[kk][tx * 4];
      double a[4] = {(double)af.x, (double)af.y, (double)af.z, (double)af.w};
      double b[4] = {(double)bf.x, (double)bf.y, (double)bf.z, (double)bf.w};
#pragma unroll
      for (int i = 0; i < 4; ++i)
#pragma unroll
        for (int j = 0; j < 4; ++j)
          acc[i][j] += a[i] * b[j];
    }
    __syncthreads();
  }
  double* prow = part + (size_t)kc * T0n * En;
#pragma unroll
  for (int i = 0; i < 4; ++i) {
    int row = m0 + ty * 4 + i;
#pragma unroll
    for (int j2 = 0; j2 < 2; ++j2) {
      double2 dv;
      dv.x = acc[i][j2 * 2 + 0];
      dv.y = acc[i][j2 * 2 + 1];
      *(double2*)&prow[(size_t)row * En + n0 + tx * 4 + j2 * 2] = dv;
    }
  }
}

// ---------------------------------------------------------------------------
// Top-8: one wave per token, shuffle butterfly. Sums KSPLIT fp64 partials.
// ---------------------------------------------------------------------------
__global__ __launch_bounds__(256) void k_topk(
    const double* __restrict__ part, int* __restrict__ sel,
    float* __restrict__ rw, int* __restrict__ cnt_e) {
  const int wid = threadIdx.x >> 6, ln = threadIdx.x & 63;
  const int t = blockIdx.x * 4 + wid;

  double v[4];
#pragma unroll
  for (int j = 0; j < 4; ++j) {
    double s = 0.0;
#pragma unroll
    for (int kc = 0; kc < KSPLIT; ++kc)
      s += part[((size_t)kc * T0n + t) * En + ln + 64 * j];
    v[j] = s;
  }

  float topv[8];
  int topi[8];
#pragma unroll
  for (int k = 0; k < 8; ++k) {
    double bv = v[0]; int bi = ln;
#pragma unroll
    for (int j = 1; j < 4; ++j) {
      int cand = ln + 64 * j;
      if (v[j] > bv || (v[j] == bv && cand < bi)) { bv = v[j]; bi = cand; }
    }
#pragma unroll
    for (int off = 32; off > 0; off >>= 1) {
      double ov = __shfl_xor(bv, off);
      int oi = __shfl_xor(bi, off);
      if (ov > bv || (ov == bv && oi < bi)) { bv = ov; bi = oi; }
    }
    topv[k] = (float)bv; topi[k] = bi;
    if ((bi & 63) == ln) v[bi >> 6] = -1e300;
  }

  if (ln < 8) {
    float m = topv[0];
    float ssum = 0.f;
#pragma unroll
    for (int k = 0; k < 8; ++k) ssum += expf(topv[k] - m);
    rw[t * 8 + ln] = expf(topv[ln] - m) / ssum;
    sel[t * 8 + ln] = topi[ln];
    atomicAdd(&cnt_e[topi[ln]], 1);
  }
}

__global__ void k_scan(const int* __restrict__ cnt_e, int* __restrict__ off_e,
                       int* __restrict__ cur_e, int* __restrict__ grp_n) {
  if (threadIdx.x == 0 && blockIdx.x == 0) {
    for (int g = 0; g < Gn; ++g) {
      int run = 0;
      for (int ei = 0; ei < EGn; ++ei) {
        int e = g * EGn + ei;
        off_e[e] = g * SEGCAP + run;
        cur_e[e] = g * SEGCAP + run;
        run += cnt_e[e];
      }
      grp_n[g] = run;
    }
  }
}

__global__ void k_scatter(const int* __restrict__ sel, int* __restrict__ cur_e,
                          int* __restrict__ rseg) {
  int i = blockIdx.x * 256 + threadIdx.x;
  int e = sel[i];
  int pos = atomicAdd(&cur_e[e], 1);
  rseg[pos] = i;
}

// ---------------------------------------------------------------------------
// h1 = H @ A_fac[g], gate+up in one block (A-fragment reuse), H f32 staged
// with on-the-fly bf16 convert. Output h1 in BF16 (its only consumer uses
// it as a bf16 A-operand). grid (T0/64, G).
// ---------------------------------------------------------------------------
__global__ __launch_bounds__(256) void k_h1_mfma(
    const float* __restrict__ H,
    const unsigned short* __restrict__ AgT, const unsigned short* __restrict__ AuT,
    unsigned short* __restrict__ h1gb, unsigned short* __restrict__ h1ub) {
  const int t0 = blockIdx.x * 64;
  const int g = blockIdx.y;
  const unsigned short* Wg = AgT + (size_t)g * Rn * Dn;
  const unsigned short* Wu = AuT + (size_t)g * Rn * Dn;

  __shared__ unsigned short As[64 * 72];
  __shared__ unsigned short Bg_l[64 * 72];
  __shared__ unsigned short Bu_l[64 * 72];
  const int tid = threadIdx.x;
  const int w = tid >> 6, ln = tid & 63;
  const int quad = ln >> 4, lane16 = ln & 15;
  const int j = tid >> 2, q = (tid & 3) * 16;

  f4v Sg[4] = {}, Su[4] = {};

  for (int k0 = 0; k0 < Dn; k0 += 64) {
#pragma unroll
    for (int i = 0; i < 4; ++i) {
      float4 v = *(const float4*)&H[(size_t)(t0 + j) * Dn + k0 + q + i * 4];
      ushort4 o;
      o.x = f2bf(v.x); o.y = f2bf(v.y); o.z = f2bf(v.z); o.w = f2bf(v.w);
      *(ushort4*)&As[j * 72 + q + i * 4] = o;
    }
    *(uint4*)&Bg_l[j * 72 + q + 0] = *(const uint4*)&Wg[(size_t)j * Dn + k0 + q + 0];
    *(uint4*)&Bg_l[j * 72 + q + 8] = *(const uint4*)&Wg[(size_t)j * Dn + k0 + q + 8];
    *(uint4*)&Bu_l[j * 72 + q + 0] = *(const uint4*)&Wu[(size_t)j * Dn + k0 + q + 0];
    *(uint4*)&Bu_l[j * 72 + q + 8] = *(const uint4*)&Wu[(size_t)j * Dn + k0 + q + 8];
    __syncthreads();
#pragma unroll
    for (int kk = 0; kk < 2; ++kk) {
      s8v a = *(const s8v*)&As[(w * 16 + lane16) * 72 + kk * 32 + quad * 8];
#pragma unroll
      for (int nt = 0; nt < 4; ++nt) {
        s8v bg = *(const s8v*)&Bg_l[(nt * 16 + lane16) * 72 + kk * 32 + quad * 8];
        s8v bu = *(const s8v*)&Bu_l[(nt * 16 + lane16) * 72 + kk * 32 + quad * 8];
        Sg[nt] = MFMA16(a, bg, Sg[nt]);
        Su[nt] = MFMA16(a, bu, Su[nt]);
      }
    }
    __syncthreads();
  }
#pragma unroll
  for (int nt = 0; nt < 4; ++nt)
#pragma unroll
    for (int r = 0; r < 4; ++r) {
      int row = t0 + w * 16 + quad * 4 + r;
      int col = g * 64 + nt * 16 + lane16;
      h1gb[(size_t)row * (Gn * Rn) + col] = f2bf(Sg[nt][r]);
      h1ub[(size_t)row * (Gn * Rn) + col] = f2bf(Su[nt][r]);
    }
}

// ---------------------------------------------------------------------------
// Per-expert core (gate/up) via MFMA: h2 = h1 @ C_e. h1 already bf16.
// ---------------------------------------------------------------------------
__global__ __launch_bounds__(256) void k_core_gu(
    const unsigned short* __restrict__ h1gb, const unsigned short* __restrict__ h1ub,
    const unsigned short* __restrict__ CgT, const unsigned short* __restrict__ CuT,
    const int* __restrict__ rseg, const int* __restrict__ off_e,
    const int* __restrict__ cnt_e,
    unsigned short* __restrict__ h2gb, unsigned short* __restrict__ h2ub) {
  const int e = blockIdx.x;
  const int ne = cnt_e[e];
  if (ne == 0) return;
  const int g = e >> 5;
  const int base = off_e[e];
  __shared__ unsigned short Bg_l[64 * 72];
  __shared__ unsigned short Bu_l[64 * 72];
  __shared__ unsigned short Ag_l[64 * 72];
  __shared__ unsigned short Au_l[64 * 72];
  __shared__ int rids[64];
  const int tid = threadIdx.x;
  const int w = tid >> 6, ln = tid & 63;
  const int quad = ln >> 4, lane16 = ln & 15;
  const int j = tid >> 2, q = (tid & 3) * 16;
  {
    const unsigned short* cg = CgT + (size_t)e * (Rn * Rn);
    const unsigned short* cu = CuT + (size_t)e * (Rn * Rn);
    *(uint4*)&Bg_l[j * 72 + q + 0] = *(const uint4*)&cg[j * 64 + q + 0];
    *(uint4*)&Bg_l[j * 72 + q + 8] = *(const uint4*)&cg[j * 64 + q + 8];
    *(uint4*)&Bu_l[j * 72 + q + 0] = *(const uint4*)&cu[j * 64 + q + 0];
    *(uint4*)&Bu_l[j * 72 + q + 8] = *(const uint4*)&cu[j * 64 + q + 8];
  }
  const int ntile = (ne + 63) >> 6;
  for (int it = 0; it < ntile; ++it) {
    int mi = it * 64 + j;
    int rid = (mi < ne) ? rseg[base + mi] : -1;
    if ((tid & 3) == 0) rids[j] = rid;
    uint4 zg = {0, 0, 0, 0}, zu = {0, 0, 0, 0};
    uint4 zg2 = {0, 0, 0, 0}, zu2 = {0, 0, 0, 0};
    if (rid >= 0) {
      const unsigned short* pg = &h1gb[(size_t)(rid >> 3) * (Gn * Rn) + g * 64 + q];
      const unsigned short* pu = &h1ub[(size_t)(rid >> 3) * (Gn * Rn) + g * 64 + q];
      zg = *(const uint4*)pg;  zg2 = *(const uint4*)(pg + 8);
      zu = *(const uint4*)pu;  zu2 = *(const uint4*)(pu + 8);
    }
    *(uint4*)&Ag_l[j * 72 + q + 0] = zg;
    *(uint4*)&Ag_l[j * 72 + q + 8] = zg2;
    *(uint4*)&Au_l[j * 72 + q + 0] = zu;
    *(uint4*)&Au_l[j * 72 + q + 8] = zu2;
    __syncthreads();
    f4v Sg[4] = {}, Su[4] = {};
#pragma unroll
    for (int kk = 0; kk < 2; ++kk) {
      s8v ag = *(const s8v*)&Ag_l[(w * 16 + lane16) * 72 + kk * 32 + quad * 8];
      s8v au = *(const s8v*)&Au_l[(w * 16 + lane16) * 72 + kk * 32 + quad * 8];
#pragma unroll
      for (int nt = 0; nt < 4; ++nt) {
        s8v bg = *(const s8v*)&Bg_l[(nt * 16 + lane16) * 72 + kk * 32 + quad * 8];
        s8v bu = *(const s8v*)&Bu_l[(nt * 16 + lane16) * 72 + kk * 32 + quad * 8];
        Sg[nt] = MFMA16(ag, bg, Sg[nt]);
        Su[nt] = MFMA16(au, bu, Su[nt]);
      }
    }
#pragma unroll
    for (int nt = 0; nt < 4; ++nt)
#pragma unroll
      for (int r = 0; r < 4; ++r) {
        int lrow = w * 16 + quad * 4 + r;
        int rid2 = rids[lrow];
        if (rid2 >= 0) {
          h2gb[(size_t)rid2 * 64 + nt * 16 + lane16] = f2bf(Sg[nt][r]);
          h2ub[(size_t)rid2 * 64 + nt * 16 + lane16] = f2bf(Su[nt][r]);
        }
      }
    __syncthreads();
  }
}

// ---------------------------------------------------------------------------
// Fused expand + down-A via MFMA (inter stays on-chip). 128-row tiles:
// 48 MFMA per B-stage section (vs 24 at 64 rows). Inter (128x64 bf16) lives
// in Bg_l(+Bu_l) after the gate/up MFMAs are done with them.
// grid (4 I-splits, NROWS/128, G).
// ---------------------------------------------------------------------------
__global__ __launch_bounds__(256) void k_expand_mfma(
    const unsigned short* __restrict__ h2gb, const unsigned short* __restrict__ h2ub,
    const unsigned short* __restrict__ BgT, const unsigned short* __restrict__ BuT,
    const unsigned short* __restrict__ AdT,
    const int* __restrict__ rseg, const int* __restrict__ grp_n,
    float* __restrict__ h1d) {
  const int g = blockIdx.z;
  const int ng = grp_n[g];
  const int m0 = blockIdx.y * 128;
  if (m0 >= ng) return;
  const int c_beg = blockIdx.x * 6;
  const int c_end = min(22, c_beg + 6);

  __shared__ unsigned short Hg_l[128 * 72];
  __shared__ unsigned short Hu_l[128 * 72];
  __shared__ unsigned short Bg_l[64 * 72];   // B_gate chunk, then inter rows 0..63
  __shared__ unsigned short Bu_l[64 * 72];   // B_up chunk, then inter rows 64..127
  __shared__ unsigned short Ad_l[64 * 72];
  __shared__ int rids[128];

  const int tid = threadIdx.x;
  const int w = tid >> 6, ln = tid & 63;
  const int quad = ln >> 4, lane16 = ln & 15;

  if (tid < 128) rids[tid] = (m0 + tid < ng) ? rseg[g * SEGCAP + m0 + tid] : -1;
  __syncthreads();
#pragma unroll
  for (int i = 0; i < 4; ++i) {
    int c = tid + i * 256;             // 1024 chunks = 128 rows x 8
    int row = c >> 3, cc = (c & 7) * 8;
    int rid = rids[row];
    uint4 zg = {0, 0, 0, 0}, zu = {0, 0, 0, 0};
    if (rid >= 0) {
      zg = *(const uint4*)&h2gb[(size_t)rid * 64 + cc];
      zu = *(const uint4*)&h2ub[(size_t)rid * 64 + cc];
    }
    *(uint4*)&Hg_l[row * 72 + cc] = zg;
    *(uint4*)&Hu_l[row * 72 + cc] = zu;
  }

  const unsigned short* Bg_base = BgT + (size_t)g * In * Rn;
  const unsigned short* Bu_base = BuT + (size_t)g * In * Rn;
  const unsigned short* Ad_base = AdT + (size_t)g * Rn * In;

  f4v P[2][4] = {};

  for (int c = c_beg; c < c_end; ++c) {
    const int i0 = c * 64;
#pragma unroll
    for (int i = 0; i < 2; ++i) {
      int cq = tid + i * 256;
      int row = cq >> 3, co = (cq & 7) * 8;
      *(uint4*)&Bg_l[row * 72 + co] = *(const uint4*)&Bg_base[(size_t)(i0 + row) * Rn + co];
      *(uint4*)&Bu_l[row * 72 + co] = *(const uint4*)&Bu_base[(size_t)(i0 + row) * Rn + co];
      *(uint4*)&Ad_l[row * 72 + co] = *(const uint4*)&Ad_base[(size_t)row * In + i0 + co];
    }
    __syncthreads();

    f4v Sg[2][4] = {}, Su[2][4] = {};
#pragma unroll
    for (int kk = 0; kk < 2; ++kk) {
      s8v ag[2], au[2], bg[4], bu[4];
#pragma unroll
      for (int mt = 0; mt < 2; ++mt) {
        ag[mt] = *(const s8v*)&Hg_l[(w * 32 + mt * 16 + lane16) * 72 + kk * 32 + quad * 8];
        au[mt] = *(const s8v*)&Hu_l[(w * 32 + mt * 16 + lane16) * 72 + kk * 32 + quad * 8];
      }
#pragma unroll
      for (int nt = 0; nt < 4; ++nt) {
        bg[nt] = *(const s8v*)&Bg_l[(nt * 16 + lane16) * 72 + kk * 32 + quad * 8];
        bu[nt] = *(const s8v*)&Bu_l[(nt * 16 + lane16) * 72 + kk * 32 + quad * 8];
      }
#pragma unroll
      for (int mt = 0; mt < 2; ++mt)
#pragma unroll
        for (int nt = 0; nt < 4; ++nt) {
          Sg[mt][nt] = MFMA16(ag[mt], bg[nt], Sg[mt][nt]);
          Su[mt][nt] = MFMA16(au[mt], bu[nt], Su[mt][nt]);
        }
    }
    __syncthreads();   // Bg_l/Bu_l reads done; reuse as inter
    {
      unsigned short* ibuf = (w < 2) ? Bg_l : Bu_l;   // rows 0..63 / 64..127
#pragma unroll
      for (int mt = 0; mt < 2; ++mt)
#pragma unroll
        for (int nt = 0; nt < 4; ++nt)
#pragma unroll
          for (int r = 0; r < 4; ++r) {
            float sg = Sg[mt][nt][r];
            float v = sg / (1.f + __expf(-sg)) * Su[mt][nt][r];
            int row = (w * 32 + mt * 16 + quad * 4 + r) & 63;
            ibuf[row * 72 + nt * 16 + lane16] = f2bf(v);
          }
    }
    __syncthreads();
#pragma unroll
    for (int kk = 0; kk < 2; ++kk) {
      s8v ai[2], bd[4];
#pragma unroll
      for (int mt = 0; mt < 2; ++mt) {
        const unsigned short* src = (w < 2) ? Bg_l : Bu_l;
        int arow = (w * 32 + mt * 16 + lane16) & 63;
        ai[mt] = *(const s8v*)&src[arow * 72 + kk * 32 + quad * 8];
      }
#pragma unroll
      for (int nt = 0; nt < 4; ++nt)
        bd[nt] = *(const s8v*)&Ad_l[(nt * 16 + lane16) * 72 + kk * 32 + quad * 8];
#pragma unroll
      for (int mt = 0; mt < 2; ++mt)
#pragma unroll
        for (int nt = 0; nt < 4; ++nt)
          P[mt][nt] = MFMA16(ai[mt], bd[nt], P[mt][nt]);
    }
    __syncthreads();   // before next chunk restages Bg_l/Bu_l/Ad_l
  }

#pragma unroll
  for (int mt = 0; mt < 2; ++mt)
#pragma unroll
    for (int nt = 0; nt < 4; ++nt)
#pragma unroll
      for (int r = 0; r < 4; ++r) {
        int lrow = w * 32 + mt * 16 + quad * 4 + r;
        int rid = rids[lrow];
        if (rid >= 0)
          atomicAdd(&h1d[(size_t)rid * 64 + nt * 16 + lane16], P[mt][nt][r]);
      }
}

// ---------------------------------------------------------------------------
// Per-expert down core via MFMA + routing weight, reduce to y[t,g,64].
// ---------------------------------------------------------------------------
__global__ __launch_bounds__(256) void k_core_down(
    const float* __restrict__ h1d, const unsigned short* __restrict__ CdT,
    const float* __restrict__ rw,
    const int* __restrict__ rseg, const int* __restrict__ off_e,
    const int* __restrict__ cnt_e,
    float* __restrict__ y) {
  const int e = blockIdx.x;
  const int ne = cnt_e[e];
  if (ne == 0) return;
  const int g = e >> 5;
  const int base = off_e[e];
  __shared__ unsigned short Bd_l[64 * 72];
  __shared__ unsigned short Ad_l[64 * 72];
  __shared__ int rids[64];
  const int tid = threadIdx.x;
  const int w = tid >> 6, ln = tid & 63;
  const int quad = ln >> 4, lane16 = ln & 15;
  const int j = tid >> 2, q = (tid & 3) * 16;
  {
    const unsigned short* cd = CdT + (size_t)e * (Rn * Rn);
    *(uint4*)&Bd_l[j * 72 + q + 0] = *(const uint4*)&cd[j * 64 + q + 0];
    *(uint4*)&Bd_l[j * 72 + q + 8] = *(const uint4*)&cd[j * 64 + q + 8];
  }
  const int ntile = (ne + 63) >> 6;
  for (int it = 0; it < ntile; ++it) {
    int mi = it * 64 + j;
    int rid = (mi < ne) ? rseg[base + mi] : -1;
    if ((tid & 3) == 0) rids[j] = rid;
#pragma unroll
    for (int i = 0; i < 4; ++i) {
      int kb = q + i * 4;
      float4 vd = {0.f, 0.f, 0.f, 0.f};
      if (rid >= 0) vd = *(const float4*)&h1d[(size_t)rid * 64 + kb];
      ushort4 od;
      od.x = f2bf(vd.x); od.y = f2bf(vd.y); od.z = f2bf(vd.z); od.w = f2bf(vd.w);
      *(ushort4*)&Ad_l[j * 72 + kb] = od;
    }
    __syncthreads();
    f4v Sd[4] = {};
#pragma unroll
    for (int kk = 0; kk < 2; ++kk) {
      s8v ad = *(const s8v*)&Ad_l[(w * 16 + lane16) * 72 + kk * 32 + quad * 8];
#pragma unroll
      for (int nt = 0; nt < 4; ++nt) {
        s8v bd = *(const s8v*)&Bd_l[(nt * 16 + lane16) * 72 + kk * 32 + quad * 8];
        Sd[nt] = MFMA16(ad, bd, Sd[nt]);
      }
    }
#pragma unroll
    for (int nt = 0; nt < 4; ++nt)
#pragma unroll
      for (int r = 0; r < 4; ++r) {
        int lrow = w * 16 + quad * 4 + r;
        int rid2 = rids[lrow];
        if (rid2 >= 0) {
          float wgt = rw[rid2];
          atomicAdd(&y[(size_t)(rid2 >> 3) * (Gn * Rn) + g * 64 + nt * 16 + lane16],
                    wgt * Sd[nt][r]);
        }
      }
    __syncthreads();
  }
}

// ---------------------------------------------------------------------------
// Combine: out[2048,2048] = y[2048,512] @ B_down-as-[512,2048], MFMA bf16.
// ---------------------------------------------------------------------------
__global__ __launch_bounds__(256) void k_combine(
    const float* __restrict__ y, const unsigned short* __restrict__ BdT,
    float* __restrict__ outp) {
  const int t0 = blockIdx.y * 128, n0 = blockIdx.x * 128;
  __shared__ unsigned short As[128 * 72];
  __shared__ unsigned short Bs[128 * 72];
  const int tid = threadIdx.x;
  const int w = tid >> 6, ln = tid & 63;
  const int quad = ln >> 4, lane16 = ln & 15;
  const int mbase = (w >> 1) * 64, nbase = (w & 1) * 64;

  f4v acc[4][4] = {};

  for (int k0 = 0; k0 < Gn * Rn; k0 += 64) {
#pragma unroll
    for (int i = 0; i < 8; ++i) {
      int c = tid + i * 256;
      int row = c >> 4, cc = (c & 15) * 4;
      float4 v = *(const float4*)&y[(size_t)(t0 + row) * (Gn * Rn) + k0 + cc];
      ushort4 o;
      o.x = f2bf(v.x); o.y = f2bf(v.y); o.z = f2bf(v.z); o.w = f2bf(v.w);
      *(ushort4*)&As[row * 72 + cc] = o;
    }
#pragma unroll
    for (int i = 0; i < 4; ++i) {
      int c = tid + i * 256;
      int row = c >> 3, cc = (c & 7) * 8;
      *(uint4*)&Bs[row * 72 + cc] = *(const uint4*)&BdT[(size_t)(n0 + row) * (Gn * Rn) + k0 + cc];
    }
    __syncthreads();
#pragma unroll
    for (int kk = 0; kk < 2; ++kk) {
      s8v a[4], b[4];
#pragma unroll
      for (int mt = 0; mt < 4; ++mt)
        a[mt] = *(const s8v*)&As[(mbase + mt * 16 + lane16) * 72 + kk * 32 + quad * 8];
#pragma unroll
      for (int nt = 0; nt < 4; ++nt)
        b[nt] = *(const s8v*)&Bs[(nbase + nt * 16 + lane16) * 72 + kk * 32 + quad * 8];
#pragma unroll
      for (int mt = 0; mt < 4; ++mt)
#pragma unroll
        for (int nt = 0; nt < 4; ++nt)
          acc[mt][nt] = MFMA16(a[mt], b[nt], acc[mt][nt]);
    }
    __syncthreads();
  }
#pragma unroll
  for (int mt = 0; mt < 4; ++mt)
#pragma unroll
    for (int nt = 0; nt < 4; ++nt)
#pragma unroll
      for (int r = 0; r < 4; ++r)
        outp[(size_t)(t0 + mbase + mt * 16 + quad * 4 + r) * Dn +
             n0 + nbase + nt * 16 + lane16] = acc[mt][nt][r];
}

// ---------------------------------------------------------------------------
extern "C" void kernel_launch(void* const* d_in, const int* in_sizes, int n_in,
                              void* d_out, int out_size, void* d_ws, size_t ws_size,
                              hipStream_t stream) {
  const float* hidden = (const float*)d_in[0];
  const float* w_gate = (const float*)d_in[1];
  const float* A_gate = (const float*)d_in[2];
  const float* C_gate = (const float*)d_in[3];
  const float* B_gate = (const float*)d_in[4];
  const float* A_up   = (const float*)d_in[5];
  const float* C_up   = (const float*)d_in[6];
  const float* B_up   = (const float*)d_in[7];
  const float* A_down = (const float*)d_in[8];
  const float* C_down = (const float*)d_in[9];
  const float* B_down = (const float*)d_in[10];
  float* out = (float*)d_out;

  // Workspace layout. part = fp64 router partials (33.55 MB at offset 0).
  // Everything below is written only AFTER k_topk consumes part
  // (stream-ordered), so the aliasing is safe.
  char* base = (char*)d_ws;
  double* part = (double*)d_ws;
  size_t o = 0;
  unsigned short* h2gb = (unsigned short*)(base + o); o += (size_t)NROWS * Rn * 2;
  unsigned short* h2ub = (unsigned short*)(base + o); o += (size_t)NROWS * Rn * 2;
  unsigned short* AgT  = (unsigned short*)(base + o); o += (size_t)Gn * Rn * Dn * 2;
  unsigned short* AuT  = (unsigned short*)(base + o); o += (size_t)Gn * Rn * Dn * 2;
  unsigned short* BgT  = (unsigned short*)(base + o); o += (size_t)Gn * In * Rn * 2;
  unsigned short* BuT  = (unsigned short*)(base + o); o += (size_t)Gn * In * Rn * 2;
  unsigned short* AdT  = (unsigned short*)(base + o); o += (size_t)Gn * Rn * In * 2;
  unsigned short* BdT  = (unsigned short*)(base + o); o += (size_t)Dn * Gn * Rn * 2;
  unsigned short* CgT  = (unsigned short*)(base + o); o += (size_t)En * Rn * Rn * 2;
  unsigned short* CuT  = (unsigned short*)(base + o); o += (size_t)En * Rn * Rn * 2;
  unsigned short* CdT  = (unsigned short*)(base + o); o += (size_t)En * Rn * Rn * 2;
  unsigned short* h1gb = (unsigned short*)(base + o); o += (size_t)T0n * Gn * Rn * 2;
  unsigned short* h1ub = (unsigned short*)(base + o); o += (size_t)T0n * Gn * Rn * 2;
  float* h1d = (float*)(base + o); o += (size_t)NROWS * Rn * 4;
  float* y   = (float*)(base + o); o += (size_t)T0n * Gn * Rn * 4;
  float* rwp = (float*)(base + o); o += (size_t)NROWS * 4;
  int* sel   = (int*)(base + o); o += (size_t)NROWS * 4;
  int* rseg  = (int*)(base + o); o += (size_t)Gn * SEGCAP * 4;
  int* cnt_e = (int*)(base + o); o += En * 4;
  int* off_e = (int*)(base + o); o += En * 4;
  int* cur_e = (int*)(base + o); o += En * 4;
  int* grp_n = (int*)(base + o); o += Gn * 4;

  hipMemsetAsync(cnt_e, 0, En * sizeof(int), stream);

  // 1) router partials (fp64 regs, fp32 LDS, split-K=8) -> exact ordering
  k_router_part<<<dim3(En / 64, T0n / 64, KSPLIT), 256, 0, stream>>>(
      hidden, w_gate, part);
  // 2) top-8 + renorm + expert counts
  k_topk<<<T0n / 4, 256, 0, stream>>>(part, sel, rwp, cnt_e);
  // 3) offsets + scatter rows by expert (expert-major => group-major)
  k_scan<<<1, 64, 0, stream>>>(cnt_e, off_e, cur_e, grp_n);
  k_scatter<<<NROWS / 256, 256, 0, stream>>>(sel, cur_e, rseg);

  // part is now dead; aliased buffers may be written.
  hipMemsetAsync(h1d, 0, (size_t)NROWS * Rn * sizeof(float), stream);
  hipMemsetAsync(y,   0, (size_t)T0n * Gn * Rn * sizeof(float), stream);

  // 4) transpose+convert all 9 weight tensors to bf16 operand layouts
  {
    TD9 D;
    D.t[0] = {A_gate, AgT, Dn, Rn, Rn / 32, (Rn / 32) * (Dn / 32), 0};
    D.t[1] = {A_up,   AuT, Dn, Rn, Rn / 32, (Rn / 32) * (Dn / 32), 1024};
    D.t[2] = {B_gate, BgT, Rn, In, In / 32, (In / 32) * (Rn / 32), 2048};
    D.t[3] = {B_up,   BuT, Rn, In, In / 32, (In / 32) * (Rn / 32), 2752};
    D.t[4] = {A_down, AdT, In, Rn, Rn / 32, (Rn / 32) * (In / 32), 3456};
    D.t[5] = {B_down, BdT, Gn * Rn, Dn, Dn / 32, (Dn / 32) * (Gn * Rn / 32), 4160};
    D.t[6] = {C_gate, CgT, Rn, Rn, 2, 4, 5184};
    D.t[7] = {C_up,   CuT, Rn, Rn, 2, 4, 6208};
    D.t[8] = {C_down, CdT, Rn, Rn, 2, 4, 7232};
    k_tcvt9<<<8256, 256, 0, stream>>>(D);
  }

  // 5) dense in-factor projections, gate+up fused (MFMA bf16, h1 out bf16)
  k_h1_mfma<<<dim3(T0n / 64, Gn), 256, 0, stream>>>(hidden, AgT, AuT, h1gb, h1ub);
  // 6) per-expert core (gate/up) via MFMA, h2 out in bf16
  k_core_gu<<<En, 256, 0, stream>>>(h1gb, h1ub, CgT, CuT,
                                    rseg, off_e, cnt_e, h2gb, h2ub);
  // 7) fused expand + down-A (MFMA; inter stays on-chip), 128-row tiles
  k_expand_mfma<<<dim3(4, NROWS / 128, Gn), 256, 0, stream>>>(
      h2gb, h2ub, BgT, BuT, AdT, rseg, grp_n, h1d);
  // 8) per-expert down core via MFMA + rw, reduce to y[t,g,:]
  k_core_down<<<En, 256, 0, stream>>>(h1d, CdT, rwp,
                                      rseg, off_e, cnt_e, y);
  // 9) combine (MFMA bf16)
  k_combine<<<dim3(Dn / 128, T0n / 128), 256, 0, stream>>>(y, BdT, out);
}

// Round 8
// 339.556 us; speedup vs baseline: 2.4645x; 1.1057x over previous
//
#include <hip/hip_runtime.h>
#include <math.h>

// Problem dims
constexpr int T0n = 2048;   // tokens
constexpr int Dn  = 2048;   // hidden
constexpr int En  = 256;    // experts
constexpr int Gn  = 8;      // groups
constexpr int EGn = 32;     // experts per group
constexpr int Rn  = 64;     // tucker rank
constexpr int In  = 1408;   // intermediate

constexpr int NROWS = T0n * 8;    // 16384 dispatched rows
constexpr int SEGCAP = NROWS;     // per-group segment capacity in rseg
constexpr int KSPLIT = 8;         // router split-K factor (R6-verified)

typedef __attribute__((ext_vector_type(8))) short s8v;    // 8 bf16
typedef __attribute__((ext_vector_type(4))) float f4v;    // 4 fp32
#define MFMA16(a, b, c) __builtin_amdgcn_mfma_f32_16x16x32_bf16(a, b, c, 0, 0, 0)

__device__ __forceinline__ unsigned short f2bf(float x) {
  unsigned int u = __float_as_uint(x);
  unsigned int r = (u + 0x7FFFu + ((u >> 16) & 1u)) >> 16;
  return (unsigned short)r;
}

// ---------------------------------------------------------------------------
// Fused batched transpose+convert for 9 weight tensors:
// src f32 [batch][rows][cols] -> dst bf16 [batch][cols][rows].
// ---------------------------------------------------------------------------
struct TD { const float* src; unsigned short* dst; int rows, cols, nbx, per_batch, base; };
struct TD9 { TD t[9]; };

__global__ __launch_bounds__(256) void k_tcvt9(TD9 D) {
  __shared__ float tbuf[32][33];
  int id = blockIdx.x;
  int ti = 0;
#pragma unroll
  for (int i = 1; i < 9; ++i) ti = (id >= D.t[i].base) ? i : ti;
  TD d = D.t[ti];
  int local = id - d.base;
  int bz = local / d.per_batch;
  int rem = local - bz * d.per_batch;
  int by = rem / d.nbx;
  int bx = rem - by * d.nbx;

  size_t boff = (size_t)bz * d.rows * d.cols;
  const float* src = d.src + boff;
  unsigned short* dst = d.dst + boff;
  int c0 = bx * 32, r0 = by * 32;
  int tx = threadIdx.x & 31, ty = threadIdx.x >> 5;   // ty 0..7
  for (int i = ty; i < 32; i += 8)
    tbuf[i][tx] = src[(size_t)(r0 + i) * d.cols + c0 + tx];
  __syncthreads();
  for (int i = ty; i < 32; i += 8)
    dst[(size_t)(c0 + i) * d.rows + r0 + tx] = f2bf(tbuf[tx][i]);
}

// ---------------------------------------------------------------------------
// Router logits, split-K, FP64 register accumulation (exact expert ordering).
// R6-VERIFIED VERSION (70 us, passed). fp32 LDS (4-byte banks), fp64 regs.
// NOTE: an fp64-MFMA variant (v_mfma_f64_16x16x4f64) FAILED in R7 — fragment
// layout assumptions unverified; do not retry without a layout probe.
// grid (E/64, T0/64, KSPLIT=8).
// ---------------------------------------------------------------------------
__global__ __launch_bounds__(256) void k_router_part(
    const float* __restrict__ A, const float* __restrict__ B,
    double* __restrict__ part) {
  __shared__ float As[32][68];   // [k][m] transposed; <=2-way banks
  __shared__ float Bs[32][68];   // [k][n]
  const int m0 = blockIdx.y * 64, n0 = blockIdx.x * 64;
  const int kc = blockIdx.z;
  const int kbeg = kc * (Dn / KSPLIT);   // 256-wide K slice
  const int tid = threadIdx.x;
  const int ty = tid >> 4, tx = tid & 15;
  const int lm = tid & 63, lk8 = (tid >> 6) * 8;   // A loader
  const int br = tid >> 3, bc = (tid & 7) * 8;     // B loader

  double acc[4][4] = {};

  for (int k0 = kbeg; k0 < kbeg + Dn / KSPLIT; k0 += 32) {
    float4 a0 = *(const float4*)&A[(size_t)(m0 + lm) * Dn + k0 + lk8];
    float4 a1 = *(const float4*)&A[(size_t)(m0 + lm) * Dn + k0 + lk8 + 4];
    As[lk8 + 0][lm] = a0.x; As[lk8 + 1][lm] = a0.y;
    As[lk8 + 2][lm] = a0.z; As[lk8 + 3][lm] = a0.w;
    As[lk8 + 4][lm] = a1.x; As[lk8 + 5][lm] = a1.y;
    As[lk8 + 6][lm] = a1.z; As[lk8 + 7][lm] = a1.w;
    *(float4*)&Bs[br][bc]     = *(const float4*)&B[(size_t)(k0 + br) * En + n0 + bc];
    *(float4*)&Bs[br][bc + 4] = *(const float4*)&B[(size_t)(k0 + br) * En + n0 + bc + 4];
    __syncthreads();
#pragma unroll
    for (int kk = 0; kk < 32; ++kk) {
      float4 af = *(const float4*)&As[kk][ty * 4];
      float4 bf = *(const float4*)&Bs[kk][tx * 4];
      double a[4] = {(double)af.x, (double)af.y, (double)af.z, (double)af.w};
      double b[4] = {(double)bf.x, (double)bf.y, (double)bf.z, (double)bf.w};
#pragma unroll
      for (int i = 0; i < 4; ++i)
#pragma unroll
        for (int j = 0; j < 4; ++j)
          acc[i][j] += a[i] * b[j];
    }
    __syncthreads();
  }
  double* prow = part + (size_t)kc * T0n * En;
#pragma unroll
  for (int i = 0; i < 4; ++i) {
    int row = m0 + ty * 4 + i;
#pragma unroll
    for (int j2 = 0; j2 < 2; ++j2) {
      double2 dv;
      dv.x = acc[i][j2 * 2 + 0];
      dv.y = acc[i][j2 * 2 + 1];
      *(double2*)&prow[(size_t)row * En + n0 + tx * 4 + j2 * 2] = dv;
    }
  }
}

// ---------------------------------------------------------------------------
// Top-8: one wave per token, shuffle butterfly. Sums KSPLIT fp64 partials.
// ---------------------------------------------------------------------------
__global__ __launch_bounds__(256) void k_topk(
    const double* __restrict__ part, int* __restrict__ sel,
    float* __restrict__ rw, int* __restrict__ cnt_e) {
  const int wid = threadIdx.x >> 6, ln = threadIdx.x & 63;
  const int t = blockIdx.x * 4 + wid;

  double v[4];
#pragma unroll
  for (int j = 0; j < 4; ++j) {
    double s = 0.0;
#pragma unroll
    for (int kc = 0; kc < KSPLIT; ++kc)
      s += part[((size_t)kc * T0n + t) * En + ln + 64 * j];
    v[j] = s;
  }

  float topv[8];
  int topi[8];
#pragma unroll
  for (int k = 0; k < 8; ++k) {
    double bv = v[0]; int bi = ln;
#pragma unroll
    for (int j = 1; j < 4; ++j) {
      int cand = ln + 64 * j;
      if (v[j] > bv || (v[j] == bv && cand < bi)) { bv = v[j]; bi = cand; }
    }
#pragma unroll
    for (int off = 32; off > 0; off >>= 1) {
      double ov = __shfl_xor(bv, off);
      int oi = __shfl_xor(bi, off);
      if (ov > bv || (ov == bv && oi < bi)) { bv = ov; bi = oi; }
    }
    topv[k] = (float)bv; topi[k] = bi;
    if ((bi & 63) == ln) v[bi >> 6] = -1e300;
  }

  if (ln < 8) {
    float m = topv[0];
    float ssum = 0.f;
#pragma unroll
    for (int k = 0; k < 8; ++k) ssum += expf(topv[k] - m);
    rw[t * 8 + ln] = expf(topv[ln] - m) / ssum;
    sel[t * 8 + ln] = topi[ln];
    atomicAdd(&cnt_e[topi[ln]], 1);
  }
}

// Parallel per-group prefix over 256 experts.
__global__ __launch_bounds__(256) void k_scan(
    const int* __restrict__ cnt_e, int* __restrict__ off_e,
    int* __restrict__ cur_e, int* __restrict__ grp_n) {
  __shared__ int c[256];
  int tid = threadIdx.x;
  c[tid] = cnt_e[tid];
  __syncthreads();
  int g = tid >> 5, ei = tid & 31;
  int run = 0;
  for (int i = 0; i < ei; ++i) run += c[(g << 5) + i];
  off_e[tid] = g * SEGCAP + run;
  cur_e[tid] = g * SEGCAP + run;
  if (ei == 31) grp_n[g] = run + c[tid];
}

__global__ void k_scatter(const int* __restrict__ sel, int* __restrict__ cur_e,
                          int* __restrict__ rseg) {
  int i = blockIdx.x * 256 + threadIdx.x;
  int e = sel[i];
  int pos = atomicAdd(&cur_e[e], 1);
  rseg[pos] = i;
}

// ---------------------------------------------------------------------------
// h1 = H @ A_fac[g]. 512 threads: waves 0-3 gate, 4-7 up (H staged once,
// 8 waves/CU for latency hiding). Output bf16. grid (T0/64, G).
// ---------------------------------------------------------------------------
__global__ __launch_bounds__(512) void k_h1_mfma(
    const float* __restrict__ H,
    const unsigned short* __restrict__ AgT, const unsigned short* __restrict__ AuT,
    unsigned short* __restrict__ h1gb, unsigned short* __restrict__ h1ub) {
  const int t0 = blockIdx.x * 64;
  const int g = blockIdx.y;
  const unsigned short* Wg = AgT + (size_t)g * Rn * Dn;
  const unsigned short* Wu = AuT + (size_t)g * Rn * Dn;

  __shared__ unsigned short As[64 * 72];
  __shared__ unsigned short Bg_l[64 * 72];
  __shared__ unsigned short Bu_l[64 * 72];
  const int tid = threadIdx.x;
  const int w = tid >> 6, ln = tid & 63;
  const int path = w >> 2, ws = w & 3;
  const int quad = ln >> 4, lane16 = ln & 15;
  const int j = tid >> 3, q = (tid & 7) * 8;   // 64 rows x 8 chunks

  f4v S[4] = {};

  for (int k0 = 0; k0 < Dn; k0 += 64) {
    {
      float4 v0 = *(const float4*)&H[(size_t)(t0 + j) * Dn + k0 + q];
      float4 v1 = *(const float4*)&H[(size_t)(t0 + j) * Dn + k0 + q + 4];
      ushort4 o0, o1;
      o0.x = f2bf(v0.x); o0.y = f2bf(v0.y); o0.z = f2bf(v0.z); o0.w = f2bf(v0.w);
      o1.x = f2bf(v1.x); o1.y = f2bf(v1.y); o1.z = f2bf(v1.z); o1.w = f2bf(v1.w);
      *(ushort4*)&As[j * 72 + q] = o0;
      *(ushort4*)&As[j * 72 + q + 4] = o1;
      *(uint4*)&Bg_l[j * 72 + q] = *(const uint4*)&Wg[(size_t)j * Dn + k0 + q];
      *(uint4*)&Bu_l[j * 72 + q] = *(const uint4*)&Wu[(size_t)j * Dn + k0 + q];
    }
    __syncthreads();
    const unsigned short* Bl = path ? Bu_l : Bg_l;
#pragma unroll
    for (int kk = 0; kk < 2; ++kk) {
      s8v a = *(const s8v*)&As[(ws * 16 + lane16) * 72 + kk * 32 + quad * 8];
#pragma unroll
      for (int nt = 0; nt < 4; ++nt) {
        s8v b = *(const s8v*)&Bl[(nt * 16 + lane16) * 72 + kk * 32 + quad * 8];
        S[nt] = MFMA16(a, b, S[nt]);
      }
    }
    __syncthreads();
  }
  unsigned short* out = path ? h1ub : h1gb;
#pragma unroll
  for (int nt = 0; nt < 4; ++nt)
#pragma unroll
    for (int r = 0; r < 4; ++r) {
      int row = t0 + ws * 16 + quad * 4 + r;
      int col = g * 64 + nt * 16 + lane16;
      out[(size_t)row * (Gn * Rn) + col] = f2bf(S[nt][r]);
    }
}

// ---------------------------------------------------------------------------
// Per-expert core (gate/up) via MFMA. 512 threads: waves 0-3 gate, 4-7 up.
// ---------------------------------------------------------------------------
__global__ __launch_bounds__(512) void k_core_gu(
    const unsigned short* __restrict__ h1gb, const unsigned short* __restrict__ h1ub,
    const unsigned short* __restrict__ CgT, const unsigned short* __restrict__ CuT,
    const int* __restrict__ rseg, const int* __restrict__ off_e,
    const int* __restrict__ cnt_e,
    unsigned short* __restrict__ h2gb, unsigned short* __restrict__ h2ub) {
  const int e = blockIdx.x;
  const int ne = cnt_e[e];
  if (ne == 0) return;
  const int g = e >> 5;
  const int base = off_e[e];
  __shared__ unsigned short Cg_l[64 * 72];
  __shared__ unsigned short Cu_l[64 * 72];
  __shared__ unsigned short Ags[64 * 72];
  __shared__ unsigned short Aus[64 * 72];
  __shared__ int rids[64];
  const int tid = threadIdx.x;
  const int w = tid >> 6, ln = tid & 63;
  const int path = w >> 2, ws = w & 3;
  const int quad = ln >> 4, lane16 = ln & 15;
  const int j = tid >> 3, q = (tid & 7) * 8;
  {
    const unsigned short* cg = CgT + (size_t)e * (Rn * Rn);
    const unsigned short* cu = CuT + (size_t)e * (Rn * Rn);
    *(uint4*)&Cg_l[j * 72 + q] = *(const uint4*)&cg[j * 64 + q];
    *(uint4*)&Cu_l[j * 72 + q] = *(const uint4*)&cu[j * 64 + q];
  }
  const int ntile = (ne + 63) >> 6;
  for (int it = 0; it < ntile; ++it) {
    int mi = it * 64 + j;
    int rid = (mi < ne) ? rseg[base + mi] : -1;
    if ((tid & 7) == 0) rids[j] = rid;
    uint4 zg = {0, 0, 0, 0}, zu = {0, 0, 0, 0};
    if (rid >= 0) {
      zg = *(const uint4*)&h1gb[(size_t)(rid >> 3) * (Gn * Rn) + g * 64 + q];
      zu = *(const uint4*)&h1ub[(size_t)(rid >> 3) * (Gn * Rn) + g * 64 + q];
    }
    *(uint4*)&Ags[j * 72 + q] = zg;
    *(uint4*)&Aus[j * 72 + q] = zu;
    __syncthreads();
    const unsigned short* Al = path ? Aus : Ags;
    const unsigned short* Cl = path ? Cu_l : Cg_l;
    f4v S[4] = {};
#pragma unroll
    for (int kk = 0; kk < 2; ++kk) {
      s8v a = *(const s8v*)&Al[(ws * 16 + lane16) * 72 + kk * 32 + quad * 8];
#pragma unroll
      for (int nt = 0; nt < 4; ++nt) {
        s8v b = *(const s8v*)&Cl[(nt * 16 + lane16) * 72 + kk * 32 + quad * 8];
        S[nt] = MFMA16(a, b, S[nt]);
      }
    }
    unsigned short* out = path ? h2ub : h2gb;
#pragma unroll
    for (int nt = 0; nt < 4; ++nt)
#pragma unroll
      for (int r = 0; r < 4; ++r) {
        int rid2 = rids[ws * 16 + quad * 4 + r];
        if (rid2 >= 0)
          out[(size_t)rid2 * 64 + nt * 16 + lane16] = f2bf(S[nt][r]);
      }
    __syncthreads();
  }
}

// ---------------------------------------------------------------------------
// Fused expand + down-A via MFMA (inter stays on-chip). 128-row tiles.
// grid (4 I-splits, NROWS/128, G).
// ---------------------------------------------------------------------------
__global__ __launch_bounds__(256) void k_expand_mfma(
    const unsigned short* __restrict__ h2gb, const unsigned short* __restrict__ h2ub,
    const unsigned short* __restrict__ BgT, const unsigned short* __restrict__ BuT,
    const unsigned short* __restrict__ AdT,
    const int* __restrict__ rseg, const int* __restrict__ grp_n,
    float* __restrict__ h1d) {
  const int g = blockIdx.z;
  const int ng = grp_n[g];
  const int m0 = blockIdx.y * 128;
  if (m0 >= ng) return;
  const int c_beg = blockIdx.x * 6;
  const int c_end = min(22, c_beg + 6);

  __shared__ unsigned short Hg_l[128 * 72];
  __shared__ unsigned short Hu_l[128 * 72];
  __shared__ unsigned short Bg_l[64 * 72];   // B_gate chunk, then inter rows 0..63
  __shared__ unsigned short Bu_l[64 * 72];   // B_up chunk, then inter rows 64..127
  __shared__ unsigned short Ad_l[64 * 72];
  __shared__ int rids[128];

  const int tid = threadIdx.x;
  const int w = tid >> 6, ln = tid & 63;
  const int quad = ln >> 4, lane16 = ln & 15;

  if (tid < 128) rids[tid] = (m0 + tid < ng) ? rseg[g * SEGCAP + m0 + tid] : -1;
  __syncthreads();
#pragma unroll
  for (int i = 0; i < 4; ++i) {
    int c = tid + i * 256;
    int row = c >> 3, cc = (c & 7) * 8;
    int rid = rids[row];
    uint4 zg = {0, 0, 0, 0}, zu = {0, 0, 0, 0};
    if (rid >= 0) {
      zg = *(const uint4*)&h2gb[(size_t)rid * 64 + cc];
      zu = *(const uint4*)&h2ub[(size_t)rid * 64 + cc];
    }
    *(uint4*)&Hg_l[row * 72 + cc] = zg;
    *(uint4*)&Hu_l[row * 72 + cc] = zu;
  }

  const unsigned short* Bg_base = BgT + (size_t)g * In * Rn;
  const unsigned short* Bu_base = BuT + (size_t)g * In * Rn;
  const unsigned short* Ad_base = AdT + (size_t)g * Rn * In;

  f4v P[2][4] = {};

  for (int c = c_beg; c < c_end; ++c) {
    const int i0 = c * 64;
#pragma unroll
    for (int i = 0; i < 2; ++i) {
      int cq = tid + i * 256;
      int row = cq >> 3, co = (cq & 7) * 8;
      *(uint4*)&Bg_l[row * 72 + co] = *(const uint4*)&Bg_base[(size_t)(i0 + row) * Rn + co];
      *(uint4*)&Bu_l[row * 72 + co] = *(const uint4*)&Bu_base[(size_t)(i0 + row) * Rn + co];
      *(uint4*)&Ad_l[row * 72 + co] = *(const uint4*)&Ad_base[(size_t)row * In + i0 + co];
    }
    __syncthreads();

    f4v Sg[2][4] = {}, Su[2][4] = {};
#pragma unroll
    for (int kk = 0; kk < 2; ++kk) {
      s8v ag[2], au[2], bg[4], bu[4];
#pragma unroll
      for (int mt = 0; mt < 2; ++mt) {
        ag[mt] = *(const s8v*)&Hg_l[(w * 32 + mt * 16 + lane16) * 72 + kk * 32 + quad * 8];
        au[mt] = *(const s8v*)&Hu_l[(w * 32 + mt * 16 + lane16) * 72 + kk * 32 + quad * 8];
      }
#pragma unroll
      for (int nt = 0; nt < 4; ++nt) {
        bg[nt] = *(const s8v*)&Bg_l[(nt * 16 + lane16) * 72 + kk * 32 + quad * 8];
        bu[nt] = *(const s8v*)&Bu_l[(nt * 16 + lane16) * 72 + kk * 32 + quad * 8];
      }
#pragma unroll
      for (int mt = 0; mt < 2; ++mt)
#pragma unroll
        for (int nt = 0; nt < 4; ++nt) {
          Sg[mt][nt] = MFMA16(ag[mt], bg[nt], Sg[mt][nt]);
          Su[mt][nt] = MFMA16(au[mt], bu[nt], Su[mt][nt]);
        }
    }
    __syncthreads();   // Bg_l/Bu_l reads done; reuse as inter
    {
      unsigned short* ibuf = (w < 2) ? Bg_l : Bu_l;   // rows 0..63 / 64..127
#pragma unroll
      for (int mt = 0; mt < 2; ++mt)
#pragma unroll
        for (int nt = 0; nt < 4; ++nt)
#pragma unroll
          for (int r = 0; r < 4; ++r) {
            float sg = Sg[mt][nt][r];
            float v = sg / (1.f + __expf(-sg)) * Su[mt][nt][r];
            int row = (w * 32 + mt * 16 + quad * 4 + r) & 63;
            ibuf[row * 72 + nt * 16 + lane16] = f2bf(v);
          }
    }
    __syncthreads();
#pragma unroll
    for (int kk = 0; kk < 2; ++kk) {
      s8v ai[2], bd[4];
#pragma unroll
      for (int mt = 0; mt < 2; ++mt) {
        const unsigned short* src = (w < 2) ? Bg_l : Bu_l;
        int arow = (w * 32 + mt * 16 + lane16) & 63;
        ai[mt] = *(const s8v*)&src[arow * 72 + kk * 32 + quad * 8];
      }
#pragma unroll
      for (int nt = 0; nt < 4; ++nt)
        bd[nt] = *(const s8v*)&Ad_l[(nt * 16 + lane16) * 72 + kk * 32 + quad * 8];
#pragma unroll
      for (int mt = 0; mt < 2; ++mt)
#pragma unroll
        for (int nt = 0; nt < 4; ++nt)
          P[mt][nt] = MFMA16(ai[mt], bd[nt], P[mt][nt]);
    }
    __syncthreads();
  }

#pragma unroll
  for (int mt = 0; mt < 2; ++mt)
#pragma unroll
    for (int nt = 0; nt < 4; ++nt)
#pragma unroll
      for (int r = 0; r < 4; ++r) {
        int lrow = w * 32 + mt * 16 + quad * 4 + r;
        int rid = rids[lrow];
        if (rid >= 0)
          atomicAdd(&h1d[(size_t)rid * 64 + nt * 16 + lane16], P[mt][nt][r]);
      }
}

// ---------------------------------------------------------------------------
// Per-expert down core via MFMA + routing weight, reduce to y[t,g,64].
// 512 threads: 128 rows/iter.
// ---------------------------------------------------------------------------
__global__ __launch_bounds__(512) void k_core_down(
    const float* __restrict__ h1d, const unsigned short* __restrict__ CdT,
    const float* __restrict__ rw,
    const int* __restrict__ rseg, const int* __restrict__ off_e,
    const int* __restrict__ cnt_e,
    float* __restrict__ y) {
  const int e = blockIdx.x;
  const int ne = cnt_e[e];
  if (ne == 0) return;
  const int g = e >> 5;
  const int base = off_e[e];
  __shared__ unsigned short Bd_l[64 * 72];
  __shared__ unsigned short Ad_l[128 * 72];
  __shared__ int rids[128];
  const int tid = threadIdx.x;
  const int w = tid >> 6, ln = tid & 63;
  const int quad = ln >> 4, lane16 = ln & 15;
  {
    int j = tid >> 3, q = (tid & 7) * 8;
    const unsigned short* cd = CdT + (size_t)e * (Rn * Rn);
    *(uint4*)&Bd_l[j * 72 + q] = *(const uint4*)&cd[j * 64 + q];
  }
  const int gj = tid >> 2, gq = (tid & 3) * 16;   // 128 rows x 4 chunks of 16
  const int ntile = (ne + 127) >> 7;
  for (int it = 0; it < ntile; ++it) {
    int mi = it * 128 + gj;
    int rid = (mi < ne) ? rseg[base + mi] : -1;
    if ((tid & 3) == 0) rids[gj] = rid;
#pragma unroll
    for (int i = 0; i < 4; ++i) {
      int kb = gq + i * 4;
      float4 vd = {0.f, 0.f, 0.f, 0.f};
      if (rid >= 0) vd = *(const float4*)&h1d[(size_t)rid * 64 + kb];
      ushort4 od;
      od.x = f2bf(vd.x); od.y = f2bf(vd.y); od.z = f2bf(vd.z); od.w = f2bf(vd.w);
      *(ushort4*)&Ad_l[gj * 72 + kb] = od;
    }
    __syncthreads();
    f4v Sd[4] = {};
#pragma unroll
    for (int kk = 0; kk < 2; ++kk) {
      s8v ad = *(const s8v*)&Ad_l[(w * 16 + lane16) * 72 + kk * 32 + quad * 8];
#pragma unroll
      for (int nt = 0; nt < 4; ++nt) {
        s8v bd = *(const s8v*)&Bd_l[(nt * 16 + lane16) * 72 + kk * 32 + quad * 8];
        Sd[nt] = MFMA16(ad, bd, Sd[nt]);
      }
    }
#pragma unroll
    for (int nt = 0; nt < 4; ++nt)
#pragma unroll
      for (int r = 0; r < 4; ++r) {
        int rid2 = rids[w * 16 + quad * 4 + r];
        if (rid2 >= 0) {
          float wgt = rw[rid2];
          atomicAdd(&y[(size_t)(rid2 >> 3) * (Gn * Rn) + g * 64 + nt * 16 + lane16],
                    wgt * Sd[nt][r]);
        }
      }
    __syncthreads();
  }
}

// ---------------------------------------------------------------------------
// Combine: out[2048,2048] = y[2048,512] @ B_down-as-[512,2048], MFMA bf16.
// ---------------------------------------------------------------------------
__global__ __launch_bounds__(256) void k_combine(
    const float* __restrict__ y, const unsigned short* __restrict__ BdT,
    float* __restrict__ outp) {
  const int t0 = blockIdx.y * 128, n0 = blockIdx.x * 128;
  __shared__ unsigned short As[128 * 72];
  __shared__ unsigned short Bs[128 * 72];
  const int tid = threadIdx.x;
  const int w = tid >> 6, ln = tid & 63;
  const int quad = ln >> 4, lane16 = ln & 15;
  const int mbase = (w >> 1) * 64, nbase = (w & 1) * 64;

  f4v acc[4][4] = {};

  for (int k0 = 0; k0 < Gn * Rn; k0 += 64) {
#pragma unroll
    for (int i = 0; i < 8; ++i) {
      int c = tid + i * 256;
      int row = c >> 4, cc = (c & 15) * 4;
      float4 v = *(const float4*)&y[(size_t)(t0 + row) * (Gn * Rn) + k0 + cc];
      ushort4 o;
      o.x = f2bf(v.x); o.y = f2bf(v.y); o.z = f2bf(v.z); o.w = f2bf(v.w);
      *(ushort4*)&As[row * 72 + cc] = o;
    }
#pragma unroll
    for (int i = 0; i < 4; ++i) {
      int c = tid + i * 256;
      int row = c >> 3, cc = (c & 7) * 8;
      *(uint4*)&Bs[row * 72 + cc] = *(const uint4*)&BdT[(size_t)(n0 + row) * (Gn * Rn) + k0 + cc];
    }
    __syncthreads();
#pragma unroll
    for (int kk = 0; kk < 2; ++kk) {
      s8v a[4], b[4];
#pragma unroll
      for (int mt = 0; mt < 4; ++mt)
        a[mt] = *(const s8v*)&As[(mbase + mt * 16 + lane16) * 72 + kk * 32 + quad * 8];
#pragma unroll
      for (int nt = 0; nt < 4; ++nt)
        b[nt] = *(const s8v*)&Bs[(nbase + nt * 16 + lane16) * 72 + kk * 32 + quad * 8];
#pragma unroll
      for (int mt = 0; mt < 4; ++mt)
#pragma unroll
        for (int nt = 0; nt < 4; ++nt)
          acc[mt][nt] = MFMA16(a[mt], b[nt], acc[mt][nt]);
    }
    __syncthreads();
  }
#pragma unroll
  for (int mt = 0; mt < 4; ++mt)
#pragma unroll
    for (int nt = 0; nt < 4; ++nt)
#pragma unroll
      for (int r = 0; r < 4; ++r)
        outp[(size_t)(t0 + mbase + mt * 16 + quad * 4 + r) * Dn +
             n0 + nbase + nt * 16 + lane16] = acc[mt][nt][r];
}

// ---------------------------------------------------------------------------
extern "C" void kernel_launch(void* const* d_in, const int* in_sizes, int n_in,
                              void* d_out, int out_size, void* d_ws, size_t ws_size,
                              hipStream_t stream) {
  const float* hidden = (const float*)d_in[0];
  const float* w_gate = (const float*)d_in[1];
  const float* A_gate = (const float*)d_in[2];
  const float* C_gate = (const float*)d_in[3];
  const float* B_gate = (const float*)d_in[4];
  const float* A_up   = (const float*)d_in[5];
  const float* C_up   = (const float*)d_in[6];
  const float* B_up   = (const float*)d_in[7];
  const float* A_down = (const float*)d_in[8];
  const float* C_down = (const float*)d_in[9];
  const float* B_down = (const float*)d_in[10];
  float* out = (float*)d_out;

  // Workspace layout. part = fp64 router partials (33.55 MB at offset 0,
  // KSPLIT=8). Everything below is written only AFTER k_topk consumes part
  // (stream-ordered), so the aliasing is safe.
  char* base = (char*)d_ws;
  double* part = (double*)d_ws;
  size_t o = 0;
  unsigned short* h2gb = (unsigned short*)(base + o); o += (size_t)NROWS * Rn * 2;
  unsigned short* h2ub = (unsigned short*)(base + o); o += (size_t)NROWS * Rn * 2;
  unsigned short* AgT  = (unsigned short*)(base + o); o += (size_t)Gn * Rn * Dn * 2;
  unsigned short* AuT  = (unsigned short*)(base + o); o += (size_t)Gn * Rn * Dn * 2;
  unsigned short* BgT  = (unsigned short*)(base + o); o += (size_t)Gn * In * Rn * 2;
  unsigned short* BuT  = (unsigned short*)(base + o); o += (size_t)Gn * In * Rn * 2;
  unsigned short* AdT  = (unsigned short*)(base + o); o += (size_t)Gn * Rn * In * 2;
  unsigned short* BdT  = (unsigned short*)(base + o); o += (size_t)Dn * Gn * Rn * 2;
  unsigned short* CgT  = (unsigned short*)(base + o); o += (size_t)En * Rn * Rn * 2;
  unsigned short* CuT  = (unsigned short*)(base + o); o += (size_t)En * Rn * Rn * 2;
  unsigned short* CdT  = (unsigned short*)(base + o); o += (size_t)En * Rn * Rn * 2;
  unsigned short* h1gb = (unsigned short*)(base + o); o += (size_t)T0n * Gn * Rn * 2;
  unsigned short* h1ub = (unsigned short*)(base + o); o += (size_t)T0n * Gn * Rn * 2;
  float* h1d = (float*)(base + o); o += (size_t)NROWS * Rn * 4;
  float* y   = (float*)(base + o); o += (size_t)T0n * Gn * Rn * 4;
  float* rwp = (float*)(base + o); o += (size_t)NROWS * 4;
  int* sel   = (int*)(base + o); o += (size_t)NROWS * 4;
  int* rseg  = (int*)(base + o); o += (size_t)Gn * SEGCAP * 4;
  int* cnt_e = (int*)(base + o); o += En * 4;
  int* off_e = (int*)(base + o); o += En * 4;
  int* cur_e = (int*)(base + o); o += En * 4;
  int* grp_n = (int*)(base + o); o += Gn * 4;

  hipMemsetAsync(cnt_e, 0, En * sizeof(int), stream);

  // 1) router partials (fp64 regs, fp32 LDS, split-K=8) -> exact ordering
  k_router_part<<<dim3(En / 64, T0n / 64, KSPLIT), 256, 0, stream>>>(
      hidden, w_gate, part);
  // 2) top-8 + renorm + expert counts
  k_topk<<<T0n / 4, 256, 0, stream>>>(part, sel, rwp, cnt_e);
  // 3) offsets (parallel prefix) + scatter rows by expert
  k_scan<<<1, 256, 0, stream>>>(cnt_e, off_e, cur_e, grp_n);
  k_scatter<<<NROWS / 256, 256, 0, stream>>>(sel, cur_e, rseg);

  // part is now dead; aliased buffers may be written.
  hipMemsetAsync(h1d, 0, (size_t)NROWS * Rn * sizeof(float), stream);
  hipMemsetAsync(y,   0, (size_t)T0n * Gn * Rn * sizeof(float), stream);

  // 4) transpose+convert all 9 weight tensors to bf16 operand layouts
  {
    TD9 D;
    D.t[0] = {A_gate, AgT, Dn, Rn, Rn / 32, (Rn / 32) * (Dn / 32), 0};
    D.t[1] = {A_up,   AuT, Dn, Rn, Rn / 32, (Rn / 32) * (Dn / 32), 1024};
    D.t[2] = {B_gate, BgT, Rn, In, In / 32, (In / 32) * (Rn / 32), 2048};
    D.t[3] = {B_up,   BuT, Rn, In, In / 32, (In / 32) * (Rn / 32), 2752};
    D.t[4] = {A_down, AdT, In, Rn, Rn / 32, (Rn / 32) * (In / 32), 3456};
    D.t[5] = {B_down, BdT, Gn * Rn, Dn, Dn / 32, (Dn / 32) * (Gn * Rn / 32), 4160};
    D.t[6] = {C_gate, CgT, Rn, Rn, 2, 4, 5184};
    D.t[7] = {C_up,   CuT, Rn, Rn, 2, 4, 6208};
    D.t[8] = {C_down, CdT, Rn, Rn, 2, 4, 7232};
    k_tcvt9<<<8256, 256, 0, stream>>>(D);
  }

  // 5) dense in-factor projections (512 thr: gate waves + up waves)
  k_h1_mfma<<<dim3(T0n / 64, Gn), 512, 0, stream>>>(hidden, AgT, AuT, h1gb, h1ub);
  // 6) per-expert core (gate/up) via MFMA (512 thr path-split)
  k_core_gu<<<En, 512, 0, stream>>>(h1gb, h1ub, CgT, CuT,
                                    rseg, off_e, cnt_e, h2gb, h2ub);
  // 7) fused expand + down-A (MFMA; inter stays on-chip), 128-row tiles
  k_expand_mfma<<<dim3(4, NROWS / 128, Gn), 256, 0, stream>>>(
      h2gb, h2ub, BgT, BuT, AdT, rseg, grp_n, h1d);
  // 8) per-expert down core via MFMA + rw (512 thr, 128 rows/iter)
  k_core_down<<<En, 512, 0, stream>>>(h1d, CdT, rwp,
                                      rseg, off_e, cnt_e, y);
  // 9) combine (MFMA bf16)
  k_combine<<<dim3(Dn / 128, T0n / 128), 256, 0, stream>>>(y, BdT, out);
}